// Round 3
// baseline (908.398 us; speedup 1.0000x reference)
//
#include <hip/hip_runtime.h>

#define TOK 2048
#define DM 2048
#define DI 4096
#define NG 8
#define NN 128
#define NH 64
#define NP 64
#define NR 8
#define PROJ_D 10304
#define PROJ_P 10368
#define CONV_D 6144
#define LSEQ 1024
#define T_TILE 16
#define NTILES (LSEQ / T_TILE)

typedef unsigned short u16;
typedef __attribute__((ext_vector_type(4))) float f32x4;
typedef __attribute__((ext_vector_type(8))) short s16x8;
typedef __attribute__((ext_vector_type(4))) unsigned short u16x4;
typedef __attribute__((ext_vector_type(4))) float frag_cd;

__device__ __forceinline__ u16 f2bf(float f) {
  union { float f; unsigned u; } x; x.f = f;
  unsigned r = (x.u + 0x7FFFu + ((x.u >> 16) & 1u)) >> 16;
  return (u16)r;
}

__device__ __forceinline__ float blockReduceSum256(float s) {
  __shared__ float red[4];
  #pragma unroll
  for (int o = 32; o > 0; o >>= 1) s += __shfl_down(s, o, 64);
  int lane = threadIdx.x & 63, wid = threadIdx.x >> 6;
  if (lane == 0) red[wid] = s;
  __syncthreads();
  return red[0] + red[1] + red[2] + red[3];
}

// ---------- fp32 -> bf16 weight conversion with zero padding ----------
__global__ __launch_bounds__(256) void cvt_bf16_pad(const float* __restrict__ src, u16* __restrict__ dst,
                                                    long n_src, long n_dst) {
  long i = ((long)blockIdx.x * 256 + threadIdx.x) * 4;
  if (i >= n_dst) return;
  u16x4 o;
  if (i < n_src) {
    f32x4 v = *(const f32x4*)&src[i];
    o.x = f2bf(v.x); o.y = f2bf(v.y); o.z = f2bf(v.z); o.w = f2bf(v.w);
  } else {
    o.x = 0; o.y = 0; o.z = 0; o.w = 0;
  }
  *(u16x4*)&dst[i] = o;
}

// ---------- h = hs + residual; new_residual = h; x = rmsnorm(h)*w -> bf16 ----------
__global__ __launch_bounds__(256) void addnorm_kernel(const float* __restrict__ hs, const float* __restrict__ res,
        const float* __restrict__ w, float* __restrict__ nres, u16* __restrict__ xbf) {
  int row = blockIdx.x;
  size_t base = (size_t)row * DM;
  int tid = threadIdx.x;
  f32x4 h[2];
  float s = 0.f;
  #pragma unroll
  for (int i = 0; i < 2; i++) {
    int off = i * 1024 + tid * 4;
    f32x4 a = *(const f32x4*)&hs[base + off];
    f32x4 b = *(const f32x4*)&res[base + off];
    f32x4 v = a + b;
    h[i] = v;
    *(f32x4*)&nres[base + off] = v;
    s += v.x * v.x + v.y * v.y + v.z * v.z + v.w * v.w;
  }
  s = blockReduceSum256(s);
  float rs = rsqrtf(s * (1.f / DM) + 1e-5f);
  #pragma unroll
  for (int i = 0; i < 2; i++) {
    int off = i * 1024 + tid * 4;
    f32x4 wv = *(const f32x4*)&w[off];
    f32x4 v = h[i];
    u16x4 o;
    o.x = f2bf(v.x * rs * wv.x);
    o.y = f2bf(v.y * rs * wv.y);
    o.z = f2bf(v.z * rs * wv.z);
    o.w = f2bf(v.w * rs * wv.w);
    *(u16x4*)&xbf[base + off] = o;
  }
}

// ---------- bf16 GEMM, C[m][n] = sum_k A[m][k]*B[n][k]  (m97 structure) ----------
__device__ __forceinline__ void gld_lds16(const void* g, void* l) {
  __builtin_amdgcn_global_load_lds((const __attribute__((address_space(1))) void*)g,
                                   (__attribute__((address_space(3))) void*)l, 16, 0, 0);
}

__global__ __launch_bounds__(256) void gemm_bt(const u16* __restrict__ A, const u16* __restrict__ Bw,
                                               float* __restrict__ C, int K, int Cstride) {
  __shared__ u16 As[128 * 32];
  __shared__ u16 Bs[128 * 32];
  int tid = threadIdx.x;
  int lane = tid & 63, w = tid >> 6;
  int wr = w >> 1, wc = w & 1;
  size_t m0 = (size_t)blockIdx.y * 128, n0 = (size_t)blockIdx.x * 128;
  const u16* Ab = A + m0 * K;
  const u16* Bb = Bw + n0 * K;
  frag_cd acc[4][4];
  #pragma unroll
  for (int i = 0; i < 4; i++)
    #pragma unroll
    for (int j = 0; j < 4; j++) acc[i][j] = (frag_cd){0.f, 0.f, 0.f, 0.f};

  int srow = w * 16 + (lane >> 2);
  int scol = (lane & 3) * 8;
  const u16* sa = Ab + (size_t)srow * K + scol;
  const u16* sb = Bb + (size_t)srow * K + scol;
  u16* la = &As[w * 16 * 32];
  u16* lb = &Bs[w * 16 * 32];
  int ro = (lane & 15) * 32 + (lane >> 4) * 8;

  for (int k0 = 0; k0 < K; k0 += 32) {
    gld_lds16(sa + k0, la);
    gld_lds16(sa + (size_t)64 * K + k0, la + 64 * 32);
    gld_lds16(sb + k0, lb);
    gld_lds16(sb + (size_t)64 * K + k0, lb + 64 * 32);
    __syncthreads();
    s16x8 a[4], b[4];
    #pragma unroll
    for (int mi = 0; mi < 4; mi++) a[mi] = *(const s16x8*)&As[(wr * 64 + mi * 16) * 32 + ro];
    #pragma unroll
    for (int ni = 0; ni < 4; ni++) b[ni] = *(const s16x8*)&Bs[(wc * 64 + ni * 16) * 32 + ro];
    #pragma unroll
    for (int mi = 0; mi < 4; mi++)
      #pragma unroll
      for (int ni = 0; ni < 4; ni++)
        acc[mi][ni] = __builtin_amdgcn_mfma_f32_16x16x32_bf16(a[mi], b[ni], acc[mi][ni], 0, 0, 0);
    __syncthreads();
  }
  size_t crow0 = m0 + wr * 64 + ((lane >> 4) * 4);
  size_t ccol0 = n0 + wc * 64 + (lane & 15);
  #pragma unroll
  for (int mi = 0; mi < 4; mi++)
    #pragma unroll
    for (int ni = 0; ni < 4; ni++)
      #pragma unroll
      for (int j = 0; j < 4; j++)
        C[(crow0 + mi * 16 + j) * Cstride + ccol0 + ni * 16] = acc[mi][ni][j];
}

// ---------- causal depthwise conv(K=4) + bias + SiLU ----------
__global__ __launch_bounds__(256) void conv_silu_kernel(const float* __restrict__ proj,
        const float* __restrict__ cw, const float* __restrict__ cb, float* __restrict__ xbc) {
  long gid = (long)blockIdx.x * 256 + threadIdx.x;
  int c4 = (int)(gid % 1536);
  long t = gid / 1536;
  int l = (int)(t & 1023);
  int c = c4 * 4;
  const float* base = proj + (size_t)t * PROJ_P + DI + c;
  f32x4 acc = *(const f32x4*)&cb[c];
  f32x4 w0 = *(const f32x4*)&cw[(c + 0) * 4];
  f32x4 w1 = *(const f32x4*)&cw[(c + 1) * 4];
  f32x4 w2 = *(const f32x4*)&cw[(c + 2) * 4];
  f32x4 w3 = *(const f32x4*)&cw[(c + 3) * 4];
  #pragma unroll
  for (int k = 0; k < 4; k++) {
    int ls = l - 3 + k;
    if (ls >= 0) {
      f32x4 v = *(const f32x4*)(base + ((long)(k - 3)) * PROJ_P);
      acc.x = fmaf(v.x, w0[k], acc.x);
      acc.y = fmaf(v.y, w1[k], acc.y);
      acc.z = fmaf(v.z, w2[k], acc.z);
      acc.w = fmaf(v.w, w3[k], acc.w);
    }
  }
  f32x4 o;
  o.x = acc.x / (1.f + expf(-acc.x));
  o.y = acc.y / (1.f + expf(-acc.y));
  o.z = acc.z / (1.f + expf(-acc.z));
  o.w = acc.w / (1.f + expf(-acc.w));
  *(f32x4*)&xbc[(size_t)t * CONV_D + c] = o;
}

// ---------- dt softplus + dA, written TRANSPOSED [b*64+h][L] ----------
__global__ __launch_bounds__(256) void dt_kernel(const float* __restrict__ proj, const float* __restrict__ dt_bias,
        const float* __restrict__ A_log, float* __restrict__ dtspT, float* __restrict__ dAvT) {
  int idx = blockIdx.x * 256 + threadIdx.x;
  int t = idx >> 6, hh = idx & 63;
  int b = t >> 10, l = t & 1023;
  float dtv = proj[(size_t)t * PROJ_P + (DI + CONV_D) + hh] + dt_bias[hh];
  float sp = (dtv > 15.f) ? dtv : log1pf(expf(dtv));
  float Ah = -expf(A_log[hh]);
  size_t o = (size_t)(b * 64 + hh) * LSEQ + l;
  dtspT[o] = sp;
  dAvT[o] = expf(sp * Ah);
}

// ---------- selective scan, time-tiled, p split 4-ways ----------
// grid = 512: xcd = bid&7 == g (L2 locality for shared B/C stream); s=bid>>3:
// pair = g + 8*(s>>5) -> (b,g); sub = s&31 = r*4+ps; p0 = ps*16.
// block: 256 threads = 16 pl x 16 nq; thread n-set = {nq*4+e} u {64+nq*4+e}; h[8].
__device__ __forceinline__ void stage_tile(const float* __restrict__ xb, int l0, int g, int r, int p0,
                                           float* BshT, float* CshT, float* XshT, int wv, int lane) {
  for (int c = wv; c < 17; c += 4) {
    if (c < 8) {
      int row = c * 2 + (lane >> 5);
      int col = (lane & 31) * 4;
      gld_lds16(xb + (size_t)(l0 + row) * CONV_D + DI + g * 128 + col, BshT + c * 256);
    } else if (c < 16) {
      int cc = c - 8;
      int row = cc * 2 + (lane >> 5);
      int col = (lane & 31) * 4;
      gld_lds16(xb + (size_t)(l0 + row) * CONV_D + DI + 1024 + g * 128 + col, CshT + cc * 256);
    } else {
      int row = lane >> 2;
      int col = (lane & 3) * 4;
      gld_lds16(xb + (size_t)(l0 + row) * CONV_D + g * 512 + r * 64 + p0 + col, XshT);
    }
  }
}

__global__ __launch_bounds__(256) void scan_kernel(const float* __restrict__ xbc, const float* __restrict__ dtspT,
        const float* __restrict__ dAvT, const float* __restrict__ Dp, float* __restrict__ y) {
  int bid = blockIdx.x;
  int xcd = bid & 7, s = bid >> 3;
  int pair = xcd | ((s >> 5) << 3);   // 0..15 = b*8+g
  int sub = s & 31;                   // r*4+ps
  int b = pair >> 3, g = pair & 7;
  int r = sub >> 2, ps = sub & 3;
  int p0 = ps * 16;
  int tid = threadIdx.x;
  int wv = tid >> 6, lane = tid & 63;
  int pl = tid >> 4, nq = tid & 15;

  __shared__ float Bsh[2][T_TILE][128];
  __shared__ float Csh[2][T_TILE][128];
  __shared__ float Xsh[2][T_TILE][16];
  __shared__ float Dtsh[LSEQ];
  __shared__ float Dash[LSEQ];

  float h[8];
  #pragma unroll
  for (int j = 0; j < 8; j++) h[j] = 0.f;
  int hidx = g * 8 + r;
  float Dv = Dp[hidx];
  const float* xb = xbc + (size_t)b * LSEQ * CONV_D;

  // one-time: whole dt/dA trace for this head -> LDS
  {
    const float* dtrow = dtspT + (size_t)(b * 64 + hidx) * LSEQ;
    const float* darow = dAvT + (size_t)(b * 64 + hidx) * LSEQ;
    f32x4 v = *(const f32x4*)&dtrow[tid * 4];
    f32x4 u = *(const f32x4*)&darow[tid * 4];
    *(f32x4*)&Dtsh[tid * 4] = v;
    *(f32x4*)&Dash[tid * 4] = u;
  }
  // prologue: stage tile 0
  stage_tile(xb, 0, g, r, p0, &Bsh[0][0][0], &Csh[0][0][0], &Xsh[0][0][0], wv, lane);
  __syncthreads();

  size_t ybase = (size_t)b * LSEQ * DI + g * 512 + r * 64 + p0 + pl;

  for (int t = 0; t < NTILES; ++t) {
    int bb = t & 1;
    if (t + 1 < NTILES)
      stage_tile(xb, (t + 1) * T_TILE, g, r, p0, &Bsh[bb ^ 1][0][0], &Csh[bb ^ 1][0][0], &Xsh[bb ^ 1][0][0], wv, lane);
    int l0 = t * T_TILE;
    float accs[T_TILE];
    #pragma unroll
    for (int i = 0; i < T_TILE; ++i) {
      int l = l0 + i;
      float dtc = Dtsh[l];
      float dac = Dash[l];
      float xp = Xsh[bb][i][pl];
      float xpd = xp * dtc;
      f32x4 b0 = *(const f32x4*)&Bsh[bb][i][nq * 4];
      f32x4 b1 = *(const f32x4*)&Bsh[bb][i][64 + nq * 4];
      f32x4 c0 = *(const f32x4*)&Csh[bb][i][nq * 4];
      f32x4 c1 = *(const f32x4*)&Csh[bb][i][64 + nq * 4];
      f32x4 a4;
      h[0] = fmaf(h[0], dac, b0.x * xpd); a4.x = h[0] * c0.x;
      h[1] = fmaf(h[1], dac, b0.y * xpd); a4.y = h[1] * c0.y;
      h[2] = fmaf(h[2], dac, b0.z * xpd); a4.z = h[2] * c0.z;
      h[3] = fmaf(h[3], dac, b0.w * xpd); a4.w = h[3] * c0.w;
      h[4] = fmaf(h[4], dac, b1.x * xpd); a4.x = fmaf(h[4], c1.x, a4.x);
      h[5] = fmaf(h[5], dac, b1.y * xpd); a4.y = fmaf(h[5], c1.y, a4.y);
      h[6] = fmaf(h[6], dac, b1.z * xpd); a4.z = fmaf(h[6], c1.z, a4.z);
      h[7] = fmaf(h[7], dac, b1.w * xpd); a4.w = fmaf(h[7], c1.w, a4.w);
      accs[i] = (a4.x + a4.y) + (a4.z + a4.w);
    }
    // batched cross-nq reduce (independent chains -> pipelined DS ops)
    #pragma unroll
    for (int i = 0; i < T_TILE; ++i) {
      float a = accs[i];
      a += __shfl_xor(a, 1, 64);
      a += __shfl_xor(a, 2, 64);
      a += __shfl_xor(a, 4, 64);
      a += __shfl_xor(a, 8, 64);
      if (nq == 0) y[ybase + (size_t)(l0 + i) * DI] = fmaf(Dv, Xsh[bb][i][pl], a);
    }
    __syncthreads();
  }
}

// ---------- y2 = rmsnorm(y * silu(z)) * gw -> bf16 ----------
__global__ __launch_bounds__(256) void gate_kernel(const float* __restrict__ y, const float* __restrict__ proj,
        const float* __restrict__ gw, u16* __restrict__ y2) {
  int row = blockIdx.x;
  const float* yr = y + (size_t)row * DI;
  const float* zr = proj + (size_t)row * PROJ_P;  // z = proj[:, 0:4096]
  int tid = threadIdx.x;
  f32x4 v[4];
  float s = 0.f;
  #pragma unroll
  for (int i = 0; i < 4; i++) {
    int off = i * 1024 + tid * 4;
    f32x4 a = *(const f32x4*)&yr[off];
    f32x4 z = *(const f32x4*)&zr[off];
    f32x4 t;
    t.x = a.x * (z.x / (1.f + expf(-z.x)));
    t.y = a.y * (z.y / (1.f + expf(-z.y)));
    t.z = a.z * (z.z / (1.f + expf(-z.z)));
    t.w = a.w * (z.w / (1.f + expf(-z.w)));
    v[i] = t;
    s += t.x * t.x + t.y * t.y + t.z * t.z + t.w * t.w;
  }
  s = blockReduceSum256(s);
  float rs = rsqrtf(s * (1.f / DI) + 1e-5f);
  #pragma unroll
  for (int i = 0; i < 4; i++) {
    int off = i * 1024 + tid * 4;
    f32x4 wv = *(const f32x4*)&gw[off];
    u16x4 o;
    o.x = f2bf(v[i].x * rs * wv.x);
    o.y = f2bf(v[i].y * rs * wv.y);
    o.z = f2bf(v[i].z * rs * wv.z);
    o.w = f2bf(v[i].w * rs * wv.w);
    *(u16x4*)&y2[(size_t)row * DI + off] = o;
  }
}

extern "C" void kernel_launch(void* const* d_in, const int* in_sizes, int n_in,
                              void* d_out, int out_size, void* d_ws, size_t ws_size,
                              hipStream_t stream) {
  (void)in_sizes; (void)n_in; (void)out_size; (void)ws_size;
  const float* hs      = (const float*)d_in[0];
  const float* res     = (const float*)d_in[1];
  const float* norm_w  = (const float*)d_in[2];
  const float* w_in    = (const float*)d_in[3];
  const float* conv_w  = (const float*)d_in[4];
  const float* conv_b  = (const float*)d_in[5];
  const float* A_log   = (const float*)d_in[6];
  const float* D_param = (const float*)d_in[7];
  const float* dt_bias = (const float*)d_in[8];
  const float* gate_w  = (const float*)d_in[9];
  const float* w_out   = (const float*)d_in[10];

  float* out  = (float*)d_out;
  float* nres = out + (size_t)TOK * DM;   // second output: new_residual

  char* ws = (char*)d_ws;
  size_t off = 0;
  u16*   WB1  = (u16*)(ws + off);   off += (size_t)PROJ_P * DM * 2;      // 42.5 MB
  u16*   WB2  = (u16*)(ws + off);   off += (size_t)DM * DI * 2;          // 16.8 MB
  u16*   XBF  = (u16*)(ws + off);   off += (size_t)TOK * DM * 2;         // 8.4 MB
  float* PROJ = (float*)(ws + off); off += (size_t)TOK * PROJ_P * 4;     // 84.9 MB
  float* XBC  = (float*)(ws + off); off += (size_t)TOK * CONV_D * 4;     // 50.3 MB
  float* DTSP = (float*)(ws + off); off += (size_t)TOK * 64 * 4;
  float* DAV  = (float*)(ws + off); off += (size_t)TOK * 64 * 4;
  float* Y    = (float*)(ws + off); off += (size_t)TOK * DI * 4;         // 33.6 MB
  u16*   Y2   = (u16*)(ws + off);   off += (size_t)TOK * DI * 2;         // 16.8 MB

  // weight conversions
  cvt_bf16_pad<<<20736, 256, 0, stream>>>(w_in, WB1, (long)PROJ_D * DM, (long)PROJ_P * DM);
  cvt_bf16_pad<<<8192, 256, 0, stream>>>(w_out, WB2, (long)DM * DI, (long)DM * DI);
  // residual add + rmsnorm
  addnorm_kernel<<<TOK, 256, 0, stream>>>(hs, res, norm_w, nres, XBF);
  // in_proj GEMM: (2048 x 2048) x (10368 x 2048)^T -> 2048 x 10368
  gemm_bt<<<dim3(PROJ_P / 128, TOK / 128), 256, 0, stream>>>(XBF, WB1, PROJ, DM, PROJ_P);
  // conv + silu on xBC slice
  conv_silu_kernel<<<(TOK * (CONV_D / 4)) / 256, 256, 0, stream>>>(PROJ, conv_w, conv_b, XBC);
  // dt softplus + dA (transposed layout)
  dt_kernel<<<(TOK * 64) / 256, 256, 0, stream>>>(PROJ, dt_bias, A_log, DTSP, DAV);
  // selective scan (+ D*xs), time-tiled, 512 blocks
  scan_kernel<<<512, 256, 0, stream>>>(XBC, DTSP, DAV, D_param, Y);
  // gated rmsnorm -> bf16
  gate_kernel<<<TOK, 256, 0, stream>>>(Y, PROJ, gate_w, Y2);
  // out_proj GEMM: (2048 x 4096) x (2048 x 4096)^T -> 2048 x 2048
  gemm_bt<<<dim3(DM / 128, TOK / 128), 256, 0, stream>>>(Y2, WB2, out, DI, DM);
}

// Round 4
// 439.186 us; speedup vs baseline: 2.0684x; 2.0684x over previous
//
#include <hip/hip_runtime.h>

#define TOK 2048
#define DM 2048
#define DI 4096
#define NG 8
#define NN 128
#define PROJ_D 10304
#define PROJ_P 10368
#define CONV_D 6144
#define LSEQ 1024
#define CHUNK 64
#define NCHUNK 16

typedef unsigned short u16;
typedef __attribute__((ext_vector_type(4))) float f32x4;
typedef __attribute__((ext_vector_type(8))) short s16x8;
typedef __attribute__((ext_vector_type(4))) unsigned short u16x4;

__device__ __forceinline__ u16 f2bf(float f) {
  union { float f; unsigned u; } x; x.f = f;
  unsigned r = (x.u + 0x7FFFu + ((x.u >> 16) & 1u)) >> 16;
  return (u16)r;
}
__device__ __forceinline__ float bf2f(u16 u) {
  union { unsigned u; float f; } x; x.u = ((unsigned)u) << 16; return x.f;
}

__device__ __forceinline__ float blockReduceSum256(float s) {
  __shared__ float red[4];
  #pragma unroll
  for (int o = 32; o > 0; o >>= 1) s += __shfl_down(s, o, 64);
  int lane = threadIdx.x & 63, wid = threadIdx.x >> 6;
  if (lane == 0) red[wid] = s;
  __syncthreads();
  return red[0] + red[1] + red[2] + red[3];
}

// ---------- fp32 -> bf16 weight conversion with zero padding ----------
__global__ __launch_bounds__(256) void cvt_bf16_pad(const float* __restrict__ src, u16* __restrict__ dst,
                                                    long n_src, long n_dst) {
  long i = ((long)blockIdx.x * 256 + threadIdx.x) * 4;
  if (i >= n_dst) return;
  u16x4 o;
  if (i < n_src) {
    f32x4 v = *(const f32x4*)&src[i];
    o.x = f2bf(v.x); o.y = f2bf(v.y); o.z = f2bf(v.z); o.w = f2bf(v.w);
  } else {
    o.x = 0; o.y = 0; o.z = 0; o.w = 0;
  }
  *(u16x4*)&dst[i] = o;
}

// ---------- h = hs + residual; new_residual = h; x = rmsnorm(h)*w -> bf16 ----------
__global__ __launch_bounds__(256) void addnorm_kernel(const float* __restrict__ hs, const float* __restrict__ res,
        const float* __restrict__ w, float* __restrict__ nres, u16* __restrict__ xbf) {
  int row = blockIdx.x;
  size_t base = (size_t)row * DM;
  int tid = threadIdx.x;
  f32x4 h[2];
  float s = 0.f;
  #pragma unroll
  for (int i = 0; i < 2; i++) {
    int off = i * 1024 + tid * 4;
    f32x4 a = *(const f32x4*)&hs[base + off];
    f32x4 b = *(const f32x4*)&res[base + off];
    f32x4 v = a + b;
    h[i] = v;
    *(f32x4*)&nres[base + off] = v;
    s += v.x * v.x + v.y * v.y + v.z * v.z + v.w * v.w;
  }
  s = blockReduceSum256(s);
  float rs = rsqrtf(s * (1.f / DM) + 1e-5f);
  #pragma unroll
  for (int i = 0; i < 2; i++) {
    int off = i * 1024 + tid * 4;
    f32x4 wv = *(const f32x4*)&w[off];
    f32x4 v = h[i];
    u16x4 o;
    o.x = f2bf(v.x * rs * wv.x);
    o.y = f2bf(v.y * rs * wv.y);
    o.z = f2bf(v.z * rs * wv.z);
    o.w = f2bf(v.w * rs * wv.w);
    *(u16x4*)&xbf[base + off] = o;
  }
}

// ---------- bf16 GEMM, C[m][n] = sum_k A[m][k]*B[n][k]  (m97 structure) ----------
__device__ __forceinline__ void gld_lds16(const void* g, void* l) {
  __builtin_amdgcn_global_load_lds((const __attribute__((address_space(1))) void*)g,
                                   (__attribute__((address_space(3))) void*)l, 16, 0, 0);
}

__global__ __launch_bounds__(256) void gemm_bt(const u16* __restrict__ A, const u16* __restrict__ Bw,
                                               float* __restrict__ C, int K, int Cstride) {
  __shared__ u16 As[128 * 32];
  __shared__ u16 Bs[128 * 32];
  int tid = threadIdx.x;
  int lane = tid & 63, w = tid >> 6;
  int wr = w >> 1, wc = w & 1;
  size_t m0 = (size_t)blockIdx.y * 128, n0 = (size_t)blockIdx.x * 128;
  const u16* Ab = A + m0 * K;
  const u16* Bb = Bw + n0 * K;
  f32x4 acc[4][4];
  #pragma unroll
  for (int i = 0; i < 4; i++)
    #pragma unroll
    for (int j = 0; j < 4; j++) acc[i][j] = (f32x4){0.f, 0.f, 0.f, 0.f};

  int srow = w * 16 + (lane >> 2);
  int scol = (lane & 3) * 8;
  const u16* sa = Ab + (size_t)srow * K + scol;
  const u16* sb = Bb + (size_t)srow * K + scol;
  u16* la = &As[w * 16 * 32];
  u16* lb = &Bs[w * 16 * 32];
  int ro = (lane & 15) * 32 + (lane >> 4) * 8;

  for (int k0 = 0; k0 < K; k0 += 32) {
    gld_lds16(sa + k0, la);
    gld_lds16(sa + (size_t)64 * K + k0, la + 64 * 32);
    gld_lds16(sb + k0, lb);
    gld_lds16(sb + (size_t)64 * K + k0, lb + 64 * 32);
    __syncthreads();
    s16x8 a[4], b[4];
    #pragma unroll
    for (int mi = 0; mi < 4; mi++) a[mi] = *(const s16x8*)&As[(wr * 64 + mi * 16) * 32 + ro];
    #pragma unroll
    for (int ni = 0; ni < 4; ni++) b[ni] = *(const s16x8*)&Bs[(wc * 64 + ni * 16) * 32 + ro];
    #pragma unroll
    for (int mi = 0; mi < 4; mi++)
      #pragma unroll
      for (int ni = 0; ni < 4; ni++)
        acc[mi][ni] = __builtin_amdgcn_mfma_f32_16x16x32_bf16(a[mi], b[ni], acc[mi][ni], 0, 0, 0);
    __syncthreads();
  }
  size_t crow0 = m0 + wr * 64 + ((lane >> 4) * 4);
  size_t ccol0 = n0 + wc * 64 + (lane & 15);
  #pragma unroll
  for (int mi = 0; mi < 4; mi++)
    #pragma unroll
    for (int ni = 0; ni < 4; ni++)
      #pragma unroll
      for (int j = 0; j < 4; j++)
        C[(crow0 + mi * 16 + j) * Cstride + ccol0 + ni * 16] = acc[mi][ni][j];
}

// ---------- causal depthwise conv(K=4) + bias + SiLU -> bf16 ----------
__global__ __launch_bounds__(256) void conv_silu_kernel(const float* __restrict__ proj,
        const float* __restrict__ cw, const float* __restrict__ cb, u16* __restrict__ xbc) {
  long gid = (long)blockIdx.x * 256 + threadIdx.x;
  int c4 = (int)(gid % 1536);
  long t = gid / 1536;
  int l = (int)(t & 1023);
  int c = c4 * 4;
  const float* base = proj + (size_t)t * PROJ_P + DI + c;
  f32x4 acc = *(const f32x4*)&cb[c];
  f32x4 w0 = *(const f32x4*)&cw[(c + 0) * 4];
  f32x4 w1 = *(const f32x4*)&cw[(c + 1) * 4];
  f32x4 w2 = *(const f32x4*)&cw[(c + 2) * 4];
  f32x4 w3 = *(const f32x4*)&cw[(c + 3) * 4];
  #pragma unroll
  for (int k = 0; k < 4; k++) {
    int ls = l - 3 + k;
    if (ls >= 0) {
      f32x4 v = *(const f32x4*)(base + ((long)(k - 3)) * PROJ_P);
      acc.x = fmaf(v.x, w0[k], acc.x);
      acc.y = fmaf(v.y, w1[k], acc.y);
      acc.z = fmaf(v.z, w2[k], acc.z);
      acc.w = fmaf(v.w, w3[k], acc.w);
    }
  }
  u16x4 o;
  o.x = f2bf(acc.x / (1.f + expf(-acc.x)));
  o.y = f2bf(acc.y / (1.f + expf(-acc.y)));
  o.z = f2bf(acc.z / (1.f + expf(-acc.z)));
  o.w = f2bf(acc.w / (1.f + expf(-acc.w)));
  *(u16x4*)&xbc[(size_t)t * CONV_D + c] = o;
}

// ---------- dt: softplus(dt+bias) and log-decay dt*A, TRANSPOSED [b*64+h][L] ----------
__global__ __launch_bounds__(256) void dt_kernel(const float* __restrict__ proj, const float* __restrict__ dt_bias,
        const float* __restrict__ A_log, float* __restrict__ dtspT, float* __restrict__ dtaT) {
  int idx = blockIdx.x * 256 + threadIdx.x;
  int t = idx >> 6, hh = idx & 63;
  int b = t >> 10, l = t & 1023;
  float dtv = proj[(size_t)t * PROJ_P + (DI + CONV_D) + hh] + dt_bias[hh];
  float sp = (dtv > 15.f) ? dtv : log1pf(expf(dtv));
  float Ah = -expf(A_log[hh]);
  size_t o = (size_t)(b * 64 + hh) * LSEQ + l;
  dtspT[o] = sp;
  dtaT[o] = sp * Ah;   // log(dA) exactly
}

// ---------- chunked SSD scan: one block per (b,h); 16 chunks of 64 steps via MFMA ----------
// y[t] = Y_intra + Y_inter + D*x;  state h[p][n] fp32 in regs (wave w owns p in [w*16,w*16+16))
__global__ __launch_bounds__(256) void ssd_kernel(const u16* __restrict__ xbc, const float* __restrict__ dtsp,
        const float* __restrict__ dta, const float* __restrict__ Dp, float* __restrict__ y) {
  int bid = blockIdx.x;
  int g = bid & 7, b = (bid >> 3) & 1, r = bid >> 4;   // bid&7==g -> 8 r-blocks of (b,g) share an XCD L2
  int h = g * 8 + r;
  int tid = threadIdx.x;
  int w = tid >> 6, lane = tid & 63;

  __shared__ u16 Bsh[64][128];   // [s][n]   (swizzled cols)
  __shared__ u16 Csh[64][128];   // [t][n]   (swizzled cols)
  __shared__ u16 Xt[64][64];     // [p][s]   (swizzled cols)
  __shared__ u16 Btw[128][64];   // [n][s] weighted by w_end[s] (swizzled cols)
  __shared__ u16 GWsh[64][64];   // [t][s]   (swizzled cols)
  __shared__ u16 Hbf[64][128];   // [p][n]   (swizzled cols)
  __shared__ float dtsh[LSEQ];
  __shared__ float Lsh[LSEQ];

  const float* dtrow = dtsp + (size_t)(b * 64 + h) * LSEQ;
  const float* dtarow = dta + (size_t)(b * 64 + h) * LSEQ;
  { f32x4 v = *(const f32x4*)&dtrow[tid * 4]; *(f32x4*)&dtsh[tid * 4] = v; }
  // per-chunk inclusive cumsum of log-decay (wave-parallel scan)
  for (int cc = w; cc < NCHUNK; cc += 4) {
    float a = dtarow[cc * 64 + lane];
    #pragma unroll
    for (int o = 1; o < 64; o <<= 1) { float t2 = __shfl_up(a, o, 64); if (lane >= o) a += t2; }
    Lsh[cc * 64 + lane] = a;
  }
  {
    u16* hp = &Hbf[0][0];
    for (int i = tid; i < 2048; i += 256) *(u16x4*)&hp[i * 4] = (u16x4){0, 0, 0, 0};
  }
  f32x4 hst[8];
  #pragma unroll
  for (int i = 0; i < 8; i++) hst[i] = (f32x4){0.f, 0.f, 0.f, 0.f};
  float Dv = Dp[h];
  const u16* xb = xbc + (size_t)b * LSEQ * CONV_D;
  int swz = (lane & 7) << 3;         // frag-read col swizzle (row = lane&15 -> row&7 == lane&7)
  __syncthreads();

  for (int c = 0; c < NCHUNK; ++c) {
    int t0c = c * 64;
    // ---- stage B, C via global_load_lds (pre-swizzled source cols) ----
    #pragma unroll
    for (int q = 0; q < 4; ++q) {
      int rowb = w * 16 + q * 4;
      int row = rowb + (lane >> 4);
      int colb = ((lane & 15) * 8) ^ ((row & 7) << 3);
      gld_lds16(xb + (size_t)(t0c + row) * CONV_D + DI + g * 128 + colb, &Bsh[rowb][0]);
      gld_lds16(xb + (size_t)(t0c + row) * CONV_D + DI + NG * NN + g * 128 + colb, &Csh[rowb][0]);
    }
    // ---- stage Xt (transpose, reg path) ----
    {
      int s = tid & 63, pq = tid >> 6;
      const u16* xr = xb + (size_t)(t0c + s) * CONV_D + g * 512 + r * 64;
      #pragma unroll
      for (int pb = 0; pb < 4; ++pb) {
        int p0 = pb * 16 + pq * 4;
        u16x4 v = *(const u16x4*)&xr[p0];
        #pragma unroll
        for (int j = 0; j < 4; ++j) {
          int p = p0 + j;
          Xt[p][s ^ ((p & 7) << 3)] = v[j];
        }
      }
    }
    // ---- stage Btw = B[s][n] * exp(L63-Ls)*dt[s], transposed (reg path) ----
    {
      int s = tid & 63, nq = tid >> 6;
      float wend = __expf(Lsh[t0c + 63] - Lsh[t0c + s]) * dtsh[t0c + s];
      const u16* br = xb + (size_t)(t0c + s) * CONV_D + DI + g * 128;
      #pragma unroll
      for (int nb = 0; nb < 8; ++nb) {
        int n0 = nb * 16 + nq * 4;
        u16x4 v = *(const u16x4*)&br[n0];
        #pragma unroll
        for (int j = 0; j < 4; ++j) {
          int n = n0 + j;
          Btw[n][s ^ ((n & 7) << 3)] = f2bf(bf2f(v[j]) * wend);
        }
      }
    }
    __syncthreads();   // A: all chunk-c operands ready (drains vmcnt for gld)

    // ---- G = C·B^T  (rows t = w*16..+16, all 64 s) ----
    s16x8 aC[4];
    #pragma unroll
    for (int k = 0; k < 4; ++k)
      aC[k] = *(const s16x8*)&Csh[w * 16 + (lane & 15)][(k * 32 + (lane >> 4) * 8) ^ swz];
    f32x4 Gacc[4];
    #pragma unroll
    for (int st = 0; st < 4; ++st) Gacc[st] = (f32x4){0.f, 0.f, 0.f, 0.f};
    #pragma unroll
    for (int st = 0; st < 4; ++st)
      #pragma unroll
      for (int k = 0; k < 4; ++k) {
        s16x8 bB = *(const s16x8*)&Bsh[st * 16 + (lane & 15)][(k * 32 + (lane >> 4) * 8) ^ swz];
        Gacc[st] = __builtin_amdgcn_mfma_f32_16x16x32_bf16(aC[k], bB, Gacc[st], 0, 0, 0);
      }
    // ---- GW = mask .* exp(Lt-Ls)*dt[s] .* G -> bf16 LDS ----
    #pragma unroll
    for (int st = 0; st < 4; ++st) {
      int s = st * 16 + (lane & 15);
      float Ls = Lsh[t0c + s], dts = dtsh[t0c + s];
      #pragma unroll
      for (int j = 0; j < 4; ++j) {
        int t = w * 16 + (lane >> 4) * 4 + j;
        float wgt = (s <= t) ? __expf(Lsh[t0c + t] - Ls) * dts : 0.f;
        GWsh[t][s ^ ((t & 7) << 3)] = f2bf(Gacc[st][j] * wgt);
      }
    }
    __syncthreads();   // B: GW + Btw visible

    // ---- Y1 = GW · X  and  Y2 = C · h_in^T ----
    f32x4 Yacc[4], Y2acc[4];
    #pragma unroll
    for (int pt = 0; pt < 4; ++pt) { Yacc[pt] = (f32x4){0.f,0.f,0.f,0.f}; Y2acc[pt] = (f32x4){0.f,0.f,0.f,0.f}; }
    s16x8 aGW[2];
    #pragma unroll
    for (int k = 0; k < 2; ++k)
      aGW[k] = *(const s16x8*)&GWsh[w * 16 + (lane & 15)][(k * 32 + (lane >> 4) * 8) ^ swz];
    #pragma unroll
    for (int pt = 0; pt < 4; ++pt) {
      #pragma unroll
      for (int k = 0; k < 2; ++k) {
        s16x8 bX = *(const s16x8*)&Xt[pt * 16 + (lane & 15)][(k * 32 + (lane >> 4) * 8) ^ swz];
        Yacc[pt] = __builtin_amdgcn_mfma_f32_16x16x32_bf16(aGW[k], bX, Yacc[pt], 0, 0, 0);
      }
      #pragma unroll
      for (int k = 0; k < 4; ++k) {
        s16x8 bH = *(const s16x8*)&Hbf[pt * 16 + (lane & 15)][(k * 32 + (lane >> 4) * 8) ^ swz];
        Y2acc[pt] = __builtin_amdgcn_mfma_f32_16x16x32_bf16(aC[k], bH, Y2acc[pt], 0, 0, 0);
      }
    }
    // ---- merge, add D*x, write y ----
    float el[4];
    #pragma unroll
    for (int j = 0; j < 4; ++j) el[j] = __expf(Lsh[t0c + w * 16 + (lane >> 4) * 4 + j]);
    #pragma unroll
    for (int pt = 0; pt < 4; ++pt) {
      int p = pt * 16 + (lane & 15);
      #pragma unroll
      for (int j = 0; j < 4; ++j) {
        int t = w * 16 + (lane >> 4) * 4 + j;
        float xv = bf2f(Xt[p][t ^ ((p & 7) << 3)]);
        float yv = Yacc[pt][j] + el[j] * Y2acc[pt][j] + Dv * xv;
        y[((size_t)b * LSEQ + t0c + t) * DI + g * 512 + r * 64 + p] = yv;
      }
    }
    // ---- state update: h = e63*h + X^T diag(w_end) B  (rows p = w*16..+16, all n) ----
    float e63 = __expf(Lsh[t0c + 63]);
    s16x8 aX[2];
    #pragma unroll
    for (int k = 0; k < 2; ++k)
      aX[k] = *(const s16x8*)&Xt[w * 16 + (lane & 15)][(k * 32 + (lane >> 4) * 8) ^ swz];
    #pragma unroll
    for (int nt = 0; nt < 8; ++nt) {
      #pragma unroll
      for (int j = 0; j < 4; ++j) hst[nt][j] *= e63;
      #pragma unroll
      for (int k = 0; k < 2; ++k) {
        s16x8 bW = *(const s16x8*)&Btw[nt * 16 + (lane & 15)][(k * 32 + (lane >> 4) * 8) ^ swz];
        hst[nt] = __builtin_amdgcn_mfma_f32_16x16x32_bf16(aX[k], bW, hst[nt], 0, 0, 0);
      }
    }
    __syncthreads();   // C: everyone done reading Hbf / chunk-c operands
    // ---- publish new state for next chunk's Y2 ----
    #pragma unroll
    for (int nt = 0; nt < 8; ++nt) {
      int n = nt * 16 + (lane & 15);
      #pragma unroll
      for (int j = 0; j < 4; ++j) {
        int p = w * 16 + (lane >> 4) * 4 + j;
        Hbf[p][n ^ ((p & 7) << 3)] = f2bf(hst[nt][j]);
      }
    }
  }
}

// ---------- y2 = rmsnorm(y * silu(z)) * gw -> bf16 ----------
__global__ __launch_bounds__(256) void gate_kernel(const float* __restrict__ y, const float* __restrict__ proj,
        const float* __restrict__ gw, u16* __restrict__ y2) {
  int row = blockIdx.x;
  const float* yr = y + (size_t)row * DI;
  const float* zr = proj + (size_t)row * PROJ_P;  // z = proj[:, 0:4096]
  int tid = threadIdx.x;
  f32x4 v[4];
  float s = 0.f;
  #pragma unroll
  for (int i = 0; i < 4; i++) {
    int off = i * 1024 + tid * 4;
    f32x4 a = *(const f32x4*)&yr[off];
    f32x4 z = *(const f32x4*)&zr[off];
    f32x4 t;
    t.x = a.x * (z.x / (1.f + expf(-z.x)));
    t.y = a.y * (z.y / (1.f + expf(-z.y)));
    t.z = a.z * (z.z / (1.f + expf(-z.z)));
    t.w = a.w * (z.w / (1.f + expf(-z.w)));
    v[i] = t;
    s += t.x * t.x + t.y * t.y + t.z * t.z + t.w * t.w;
  }
  s = blockReduceSum256(s);
  float rs = rsqrtf(s * (1.f / DI) + 1e-5f);
  #pragma unroll
  for (int i = 0; i < 4; i++) {
    int off = i * 1024 + tid * 4;
    f32x4 wv = *(const f32x4*)&gw[off];
    u16x4 o;
    o.x = f2bf(v[i].x * rs * wv.x);
    o.y = f2bf(v[i].y * rs * wv.y);
    o.z = f2bf(v[i].z * rs * wv.z);
    o.w = f2bf(v[i].w * rs * wv.w);
    *(u16x4*)&y2[(size_t)row * DI + off] = o;
  }
}

extern "C" void kernel_launch(void* const* d_in, const int* in_sizes, int n_in,
                              void* d_out, int out_size, void* d_ws, size_t ws_size,
                              hipStream_t stream) {
  (void)in_sizes; (void)n_in; (void)out_size; (void)ws_size;
  const float* hs      = (const float*)d_in[0];
  const float* res     = (const float*)d_in[1];
  const float* norm_w  = (const float*)d_in[2];
  const float* w_in    = (const float*)d_in[3];
  const float* conv_w  = (const float*)d_in[4];
  const float* conv_b  = (const float*)d_in[5];
  const float* A_log   = (const float*)d_in[6];
  const float* D_param = (const float*)d_in[7];
  const float* dt_bias = (const float*)d_in[8];
  const float* gate_w  = (const float*)d_in[9];
  const float* w_out   = (const float*)d_in[10];

  float* out  = (float*)d_out;
  float* nres = out + (size_t)TOK * DM;   // second output: new_residual

  char* ws = (char*)d_ws;
  size_t off = 0;
  u16*   WB1  = (u16*)(ws + off);   off += (size_t)PROJ_P * DM * 2;      // 42.5 MB
  u16*   WB2  = (u16*)(ws + off);   off += (size_t)DM * DI * 2;          // 16.8 MB
  u16*   XBF  = (u16*)(ws + off);   off += (size_t)TOK * DM * 2;         // 8.4 MB
  float* PROJ = (float*)(ws + off); off += (size_t)TOK * PROJ_P * 4;     // 84.9 MB
  u16*   XBC  = (u16*)(ws + off);   off += (size_t)TOK * CONV_D * 4;     // (bf16, over-alloc ok)
  float* DTSP = (float*)(ws + off); off += (size_t)TOK * 64 * 4;
  float* DTA  = (float*)(ws + off); off += (size_t)TOK * 64 * 4;
  float* Y    = (float*)(ws + off); off += (size_t)TOK * DI * 4;         // 33.6 MB
  u16*   Y2   = (u16*)(ws + off);   off += (size_t)TOK * DI * 2;         // 16.8 MB

  // weight conversions
  cvt_bf16_pad<<<20736, 256, 0, stream>>>(w_in, WB1, (long)PROJ_D * DM, (long)PROJ_P * DM);
  cvt_bf16_pad<<<8192, 256, 0, stream>>>(w_out, WB2, (long)DM * DI, (long)DM * DI);
  // residual add + rmsnorm
  addnorm_kernel<<<TOK, 256, 0, stream>>>(hs, res, norm_w, nres, XBF);
  // in_proj GEMM: (2048 x 2048) x (10368 x 2048)^T -> 2048 x 10368
  gemm_bt<<<dim3(PROJ_P / 128, TOK / 128), 256, 0, stream>>>(XBF, WB1, PROJ, DM, PROJ_P);
  // conv + silu on xBC slice -> bf16
  conv_silu_kernel<<<(TOK * (CONV_D / 4)) / 256, 256, 0, stream>>>(PROJ, conv_w, conv_b, XBC);
  // dt softplus + log-decay (transposed layout)
  dt_kernel<<<(TOK * 64) / 256, 256, 0, stream>>>(PROJ, dt_bias, A_log, DTSP, DTA);
  // chunked SSD scan (+ D*xs): 128 blocks = (b,h)
  ssd_kernel<<<128, 256, 0, stream>>>(XBC, DTSP, DTA, D_param, Y);
  // gated rmsnorm -> bf16
  gate_kernel<<<TOK, 256, 0, stream>>>(Y, PROJ, gate_w, Y2);
  // out_proj GEMM: (2048 x 4096) x (2048 x 4096)^T -> 2048 x 2048
  gemm_bt<<<dim3(DM / 128, TOK / 128), 256, 0, stream>>>(Y2, WB2, out, DI, DM);
}

// Round 5
// 437.414 us; speedup vs baseline: 2.0767x; 1.0041x over previous
//
#include <hip/hip_runtime.h>

#define TOK 2048
#define DM 2048
#define DI 4096
#define NG 8
#define NN 128
#define PROJ_D 10304
#define PROJ_P 10496
#define CONV_D 6144
#define LSEQ 1024
#define CHUNK 64
#define NCHUNK 16

typedef unsigned short u16;
typedef __attribute__((ext_vector_type(4))) float f32x4;
typedef __attribute__((ext_vector_type(8))) short s16x8;
typedef __attribute__((ext_vector_type(4))) unsigned short u16x4;

__device__ __forceinline__ u16 f2bf(float f) {
  union { float f; unsigned u; } x; x.f = f;
  unsigned r = (x.u + 0x7FFFu + ((x.u >> 16) & 1u)) >> 16;
  return (u16)r;
}
__device__ __forceinline__ float bf2f(u16 u) {
  union { unsigned u; float f; } x; x.u = ((unsigned)u) << 16; return x.f;
}

__device__ __forceinline__ float blockReduceSum256(float s) {
  __shared__ float red[4];
  #pragma unroll
  for (int o = 32; o > 0; o >>= 1) s += __shfl_down(s, o, 64);
  int lane = threadIdx.x & 63, wid = threadIdx.x >> 6;
  if (lane == 0) red[wid] = s;
  __syncthreads();
  return red[0] + red[1] + red[2] + red[3];
}

// ---------- fp32 -> bf16 weight conversion with zero padding ----------
__global__ __launch_bounds__(256) void cvt_bf16_pad(const float* __restrict__ src, u16* __restrict__ dst,
                                                    long n_src, long n_dst) {
  long i = ((long)blockIdx.x * 256 + threadIdx.x) * 4;
  if (i >= n_dst) return;
  u16x4 o;
  if (i < n_src) {
    f32x4 v = *(const f32x4*)&src[i];
    o.x = f2bf(v.x); o.y = f2bf(v.y); o.z = f2bf(v.z); o.w = f2bf(v.w);
  } else {
    o.x = 0; o.y = 0; o.z = 0; o.w = 0;
  }
  *(u16x4*)&dst[i] = o;
}

// ---------- h = hs + residual; new_residual = h; x = rmsnorm(h)*w -> bf16 ----------
__global__ __launch_bounds__(256) void addnorm_kernel(const float* __restrict__ hs, const float* __restrict__ res,
        const float* __restrict__ w, float* __restrict__ nres, u16* __restrict__ xbf) {
  int row = blockIdx.x;
  size_t base = (size_t)row * DM;
  int tid = threadIdx.x;
  f32x4 h[2];
  float s = 0.f;
  #pragma unroll
  for (int i = 0; i < 2; i++) {
    int off = i * 1024 + tid * 4;
    f32x4 a = *(const f32x4*)&hs[base + off];
    f32x4 b = *(const f32x4*)&res[base + off];
    f32x4 v = a + b;
    h[i] = v;
    *(f32x4*)&nres[base + off] = v;
    s += v.x * v.x + v.y * v.y + v.z * v.z + v.w * v.w;
  }
  s = blockReduceSum256(s);
  float rs = rsqrtf(s * (1.f / DM) + 1e-5f);
  #pragma unroll
  for (int i = 0; i < 2; i++) {
    int off = i * 1024 + tid * 4;
    f32x4 wv = *(const f32x4*)&w[off];
    f32x4 v = h[i];
    u16x4 o;
    o.x = f2bf(v.x * rs * wv.x);
    o.y = f2bf(v.y * rs * wv.y);
    o.z = f2bf(v.z * rs * wv.z);
    o.w = f2bf(v.w * rs * wv.w);
    *(u16x4*)&xbf[base + off] = o;
  }
}

__device__ __forceinline__ void gld_lds16(const void* g, void* l) {
  __builtin_amdgcn_global_load_lds((const __attribute__((address_space(1))) void*)g,
                                   (__attribute__((address_space(3))) void*)l, 16, 0, 0);
}

// ---------- 256x256 deep-pipelined bf16 GEMM, C[m][n] = sum_k A[m][k]*B[n][k] ----------
// 8 waves (2x4), BK=64, LDS 128KiB dbuf, col^((row&7)<<3) swizzle (both-sides),
// 4 phases/K-tile {ds_read | stage half-tile | barrier | setprio MFMA | barrier},
// counted vmcnt(2) once per K-tile (next tile's 8 loads stay in flight).
__global__ __launch_bounds__(512, 2) void gemm256(const u16* __restrict__ A, const u16* __restrict__ Bw,
                                                  float* __restrict__ C, int K, int Cstride, int nbx) {
  __shared__ u16 As[2][256][64];
  __shared__ u16 Bs[2][256][64];
  int tid = threadIdx.x;
  int lane = tid & 63, w = tid >> 6;
  int wr = w >> 2, wc = w & 3;
  int cpx = gridDim.x >> 3;                       // grid must be multiple of 8
  int bid = blockIdx.x;
  int lb = (bid & 7) * cpx + (bid >> 3);          // bijective XCD swizzle
  int by = lb / nbx, bx = lb - by * nbx;
  size_t m0 = (size_t)by * 256, n0 = (size_t)bx * 256;
  const u16* Ab = A + m0 * K;
  const u16* Bb = Bw + n0 * K;

  f32x4 acc[8][4];
  #pragma unroll
  for (int i = 0; i < 8; ++i)
    #pragma unroll
    for (int j = 0; j < 4; ++j) acc[i][j] = (f32x4){0.f, 0.f, 0.f, 0.f};

  int l3 = lane >> 3, l7 = lane & 7;
  int colsw = 8 * (l7 ^ l3);                      // pre-swizzled source col
  int fr = lane & 15, fq = lane >> 4;
  int pc0 = (fq * 8) ^ ((fr & 7) << 3);           // frag phys col, ks=0
  int pc1 = pc0 ^ 32;                             // ks=1

  auto STAGE = [&](int d, int kt, int half) {     // half: 0,1=A halves; 2,3=B halves
    #pragma unroll
    for (int j = 0; j < 2; ++j) {
      int rr = (half & 1) * 128 + (w * 2 + j) * 8;
      const u16* src = (half < 2) ? Ab : Bb;
      u16* dst = (half < 2) ? &As[d][rr][0] : &Bs[d][rr][0];
      gld_lds16(src + (size_t)(rr + l3) * K + kt * 64 + colsw, dst);
    }
  };

  int nkt = K >> 6;
  STAGE(0, 0, 0); STAGE(0, 0, 1); STAGE(0, 0, 2); STAGE(0, 0, 3);

  for (int kt = 0; kt < nkt; ++kt) {
    int d = kt & 1, nd = d ^ 1;
    const bool pre = (kt + 1 < nkt);
    // ---- phase 0: validate tile kt, read B-frags + A-quad0, MFMA q0 ----
    if (pre) {
      STAGE(nd, kt + 1, 0);
      asm volatile("s_waitcnt vmcnt(2)" ::: "memory");
    } else {
      asm volatile("s_waitcnt vmcnt(0)" ::: "memory");
    }
    __builtin_amdgcn_s_barrier();
    s16x8 b[4][2];
    #pragma unroll
    for (int ni = 0; ni < 4; ++ni) {
      b[ni][0] = *(const s16x8*)&Bs[d][wc * 64 + ni * 16 + fr][pc0];
      b[ni][1] = *(const s16x8*)&Bs[d][wc * 64 + ni * 16 + fr][pc1];
    }
    {
      s16x8 a0[2][2];
      #pragma unroll
      for (int mi = 0; mi < 2; ++mi) {
        a0[mi][0] = *(const s16x8*)&As[d][wr * 128 + mi * 16 + fr][pc0];
        a0[mi][1] = *(const s16x8*)&As[d][wr * 128 + mi * 16 + fr][pc1];
      }
      __builtin_amdgcn_s_setprio(1);
      #pragma unroll
      for (int mi = 0; mi < 2; ++mi)
        #pragma unroll
        for (int ni = 0; ni < 4; ++ni) {
          acc[mi][ni] = __builtin_amdgcn_mfma_f32_16x16x32_bf16(a0[mi][0], b[ni][0], acc[mi][ni], 0, 0, 0);
          acc[mi][ni] = __builtin_amdgcn_mfma_f32_16x16x32_bf16(a0[mi][1], b[ni][1], acc[mi][ni], 0, 0, 0);
        }
      __builtin_amdgcn_s_setprio(0);
    }
    __builtin_amdgcn_s_barrier();
    // ---- phases 1..3 ----
    #pragma unroll
    for (int q = 1; q < 4; ++q) {
      s16x8 a[2][2];
      #pragma unroll
      for (int mi = 0; mi < 2; ++mi) {
        a[mi][0] = *(const s16x8*)&As[d][wr * 128 + q * 32 + mi * 16 + fr][pc0];
        a[mi][1] = *(const s16x8*)&As[d][wr * 128 + q * 32 + mi * 16 + fr][pc1];
      }
      if (pre) STAGE(nd, kt + 1, q);
      __builtin_amdgcn_s_barrier();
      __builtin_amdgcn_s_setprio(1);
      #pragma unroll
      for (int mi = 0; mi < 2; ++mi)
        #pragma unroll
        for (int ni = 0; ni < 4; ++ni) {
          acc[q * 2 + mi][ni] = __builtin_amdgcn_mfma_f32_16x16x32_bf16(a[mi][0], b[ni][0], acc[q * 2 + mi][ni], 0, 0, 0);
          acc[q * 2 + mi][ni] = __builtin_amdgcn_mfma_f32_16x16x32_bf16(a[mi][1], b[ni][1], acc[q * 2 + mi][ni], 0, 0, 0);
        }
      __builtin_amdgcn_s_setprio(0);
      __builtin_amdgcn_s_barrier();
    }
  }
  // ---- epilogue ----
  size_t crow0 = m0 + wr * 128 + fq * 4;
  size_t ccol0 = n0 + wc * 64 + fr;
  #pragma unroll
  for (int mf = 0; mf < 8; ++mf)
    #pragma unroll
    for (int ni = 0; ni < 4; ++ni)
      #pragma unroll
      for (int j = 0; j < 4; ++j)
        C[(crow0 + mf * 16 + j) * Cstride + ccol0 + ni * 16] = acc[mf][ni][j];
}

// ---------- bf16 GEMM, 128^2 m97 structure (kept for out_proj) ----------
__global__ __launch_bounds__(256) void gemm_bt(const u16* __restrict__ A, const u16* __restrict__ Bw,
                                               float* __restrict__ C, int K, int Cstride) {
  __shared__ u16 As[128 * 32];
  __shared__ u16 Bs[128 * 32];
  int tid = threadIdx.x;
  int lane = tid & 63, w = tid >> 6;
  int wr = w >> 1, wc = w & 1;
  size_t m0 = (size_t)blockIdx.y * 128, n0 = (size_t)blockIdx.x * 128;
  const u16* Ab = A + m0 * K;
  const u16* Bb = Bw + n0 * K;
  f32x4 acc[4][4];
  #pragma unroll
  for (int i = 0; i < 4; i++)
    #pragma unroll
    for (int j = 0; j < 4; j++) acc[i][j] = (f32x4){0.f, 0.f, 0.f, 0.f};

  int srow = w * 16 + (lane >> 2);
  int scol = (lane & 3) * 8;
  const u16* sa = Ab + (size_t)srow * K + scol;
  const u16* sb = Bb + (size_t)srow * K + scol;
  u16* la = &As[w * 16 * 32];
  u16* lb = &Bs[w * 16 * 32];
  int ro = (lane & 15) * 32 + (lane >> 4) * 8;

  for (int k0 = 0; k0 < K; k0 += 32) {
    gld_lds16(sa + k0, la);
    gld_lds16(sa + (size_t)64 * K + k0, la + 64 * 32);
    gld_lds16(sb + k0, lb);
    gld_lds16(sb + (size_t)64 * K + k0, lb + 64 * 32);
    __syncthreads();
    s16x8 a[4], b[4];
    #pragma unroll
    for (int mi = 0; mi < 4; mi++) a[mi] = *(const s16x8*)&As[(wr * 64 + mi * 16) * 32 + ro];
    #pragma unroll
    for (int ni = 0; ni < 4; ni++) b[ni] = *(const s16x8*)&Bs[(wc * 64 + ni * 16) * 32 + ro];
    #pragma unroll
    for (int mi = 0; mi < 4; mi++)
      #pragma unroll
      for (int ni = 0; ni < 4; ni++)
        acc[mi][ni] = __builtin_amdgcn_mfma_f32_16x16x32_bf16(a[mi], b[ni], acc[mi][ni], 0, 0, 0);
    __syncthreads();
  }
  size_t crow0 = m0 + wr * 64 + ((lane >> 4) * 4);
  size_t ccol0 = n0 + wc * 64 + (lane & 15);
  #pragma unroll
  for (int mi = 0; mi < 4; mi++)
    #pragma unroll
    for (int ni = 0; ni < 4; ni++)
      #pragma unroll
      for (int j = 0; j < 4; j++)
        C[(crow0 + mi * 16 + j) * Cstride + ccol0 + ni * 16] = acc[mi][ni][j];
}

// ---------- causal depthwise conv(K=4) + bias + SiLU -> bf16 ----------
__global__ __launch_bounds__(256) void conv_silu_kernel(const float* __restrict__ proj,
        const float* __restrict__ cw, const float* __restrict__ cb, u16* __restrict__ xbc) {
  long gid = (long)blockIdx.x * 256 + threadIdx.x;
  int c4 = (int)(gid % 1536);
  long t = gid / 1536;
  int l = (int)(t & 1023);
  int c = c4 * 4;
  const float* base = proj + (size_t)t * PROJ_P + DI + c;
  f32x4 acc = *(const f32x4*)&cb[c];
  f32x4 w0 = *(const f32x4*)&cw[(c + 0) * 4];
  f32x4 w1 = *(const f32x4*)&cw[(c + 1) * 4];
  f32x4 w2 = *(const f32x4*)&cw[(c + 2) * 4];
  f32x4 w3 = *(const f32x4*)&cw[(c + 3) * 4];
  #pragma unroll
  for (int k = 0; k < 4; k++) {
    int ls = l - 3 + k;
    if (ls >= 0) {
      f32x4 v = *(const f32x4*)(base + ((long)(k - 3)) * PROJ_P);
      acc.x = fmaf(v.x, w0[k], acc.x);
      acc.y = fmaf(v.y, w1[k], acc.y);
      acc.z = fmaf(v.z, w2[k], acc.z);
      acc.w = fmaf(v.w, w3[k], acc.w);
    }
  }
  u16x4 o;
  o.x = f2bf(acc.x / (1.f + expf(-acc.x)));
  o.y = f2bf(acc.y / (1.f + expf(-acc.y)));
  o.z = f2bf(acc.z / (1.f + expf(-acc.z)));
  o.w = f2bf(acc.w / (1.f + expf(-acc.w)));
  *(u16x4*)&xbc[(size_t)t * CONV_D + c] = o;
}

// ---------- dt: softplus(dt+bias) and log-decay dt*A, TRANSPOSED [b*64+h][L] ----------
__global__ __launch_bounds__(256) void dt_kernel(const float* __restrict__ proj, const float* __restrict__ dt_bias,
        const float* __restrict__ A_log, float* __restrict__ dtspT, float* __restrict__ dtaT) {
  int idx = blockIdx.x * 256 + threadIdx.x;
  int t = idx >> 6, hh = idx & 63;
  int b = t >> 10, l = t & 1023;
  float dtv = proj[(size_t)t * PROJ_P + (DI + CONV_D) + hh] + dt_bias[hh];
  float sp = (dtv > 15.f) ? dtv : log1pf(expf(dtv));
  float Ah = -expf(A_log[hh]);
  size_t o = (size_t)(b * 64 + hh) * LSEQ + l;
  dtspT[o] = sp;
  dtaT[o] = sp * Ah;   // log(dA) exactly
}

// ---------- chunked SSD scan: one block per (b,h); 16 chunks of 64 steps via MFMA ----------
__global__ __launch_bounds__(256) void ssd_kernel(const u16* __restrict__ xbc, const float* __restrict__ dtsp,
        const float* __restrict__ dta, const float* __restrict__ Dp, float* __restrict__ y) {
  int bid = blockIdx.x;
  int g = bid & 7, b = (bid >> 3) & 1, r = bid >> 4;
  int h = g * 8 + r;
  int tid = threadIdx.x;
  int w = tid >> 6, lane = tid & 63;

  __shared__ u16 Bsh[64][128];
  __shared__ u16 Csh[64][128];
  __shared__ u16 Xt[64][64];
  __shared__ u16 Btw[128][64];
  __shared__ u16 GWsh[64][64];
  __shared__ u16 Hbf[64][128];
  __shared__ float dtsh[LSEQ];
  __shared__ float Lsh[LSEQ];

  const float* dtrow = dtsp + (size_t)(b * 64 + h) * LSEQ;
  const float* dtarow = dta + (size_t)(b * 64 + h) * LSEQ;
  { f32x4 v = *(const f32x4*)&dtrow[tid * 4]; *(f32x4*)&dtsh[tid * 4] = v; }
  for (int cc = w; cc < NCHUNK; cc += 4) {
    float a = dtarow[cc * 64 + lane];
    #pragma unroll
    for (int o = 1; o < 64; o <<= 1) { float t2 = __shfl_up(a, o, 64); if (lane >= o) a += t2; }
    Lsh[cc * 64 + lane] = a;
  }
  {
    u16* hp = &Hbf[0][0];
    for (int i = tid; i < 2048; i += 256) *(u16x4*)&hp[i * 4] = (u16x4){0, 0, 0, 0};
  }
  f32x4 hst[8];
  #pragma unroll
  for (int i = 0; i < 8; i++) hst[i] = (f32x4){0.f, 0.f, 0.f, 0.f};
  float Dv = Dp[h];
  const u16* xb = xbc + (size_t)b * LSEQ * CONV_D;
  int swz = (lane & 7) << 3;
  __syncthreads();

  for (int c = 0; c < NCHUNK; ++c) {
    int t0c = c * 64;
    #pragma unroll
    for (int q = 0; q < 4; ++q) {
      int rowb = w * 16 + q * 4;
      int row = rowb + (lane >> 4);
      int colb = ((lane & 15) * 8) ^ ((row & 7) << 3);
      gld_lds16(xb + (size_t)(t0c + row) * CONV_D + DI + g * 128 + colb, &Bsh[rowb][0]);
      gld_lds16(xb + (size_t)(t0c + row) * CONV_D + DI + NG * NN + g * 128 + colb, &Csh[rowb][0]);
    }
    {
      int s = tid & 63, pq = tid >> 6;
      const u16* xr = xb + (size_t)(t0c + s) * CONV_D + g * 512 + r * 64;
      #pragma unroll
      for (int pb = 0; pb < 4; ++pb) {
        int p0 = pb * 16 + pq * 4;
        u16x4 v = *(const u16x4*)&xr[p0];
        #pragma unroll
        for (int j = 0; j < 4; ++j) {
          int p = p0 + j;
          Xt[p][s ^ ((p & 7) << 3)] = v[j];
        }
      }
    }
    {
      int s = tid & 63, nq = tid >> 6;
      float wend = __expf(Lsh[t0c + 63] - Lsh[t0c + s]) * dtsh[t0c + s];
      const u16* br = xb + (size_t)(t0c + s) * CONV_D + DI + g * 128;
      #pragma unroll
      for (int nb = 0; nb < 8; ++nb) {
        int n0 = nb * 16 + nq * 4;
        u16x4 v = *(const u16x4*)&br[n0];
        #pragma unroll
        for (int j = 0; j < 4; ++j) {
          int n = n0 + j;
          Btw[n][s ^ ((n & 7) << 3)] = f2bf(bf2f(v[j]) * wend);
        }
      }
    }
    __syncthreads();

    s16x8 aC[4];
    #pragma unroll
    for (int k = 0; k < 4; ++k)
      aC[k] = *(const s16x8*)&Csh[w * 16 + (lane & 15)][(k * 32 + (lane >> 4) * 8) ^ swz];
    f32x4 Gacc[4];
    #pragma unroll
    for (int st = 0; st < 4; ++st) Gacc[st] = (f32x4){0.f, 0.f, 0.f, 0.f};
    #pragma unroll
    for (int st = 0; st < 4; ++st)
      #pragma unroll
      for (int k = 0; k < 4; ++k) {
        s16x8 bB = *(const s16x8*)&Bsh[st * 16 + (lane & 15)][(k * 32 + (lane >> 4) * 8) ^ swz];
        Gacc[st] = __builtin_amdgcn_mfma_f32_16x16x32_bf16(aC[k], bB, Gacc[st], 0, 0, 0);
      }
    #pragma unroll
    for (int st = 0; st < 4; ++st) {
      int s = st * 16 + (lane & 15);
      float Ls = Lsh[t0c + s], dts = dtsh[t0c + s];
      #pragma unroll
      for (int j = 0; j < 4; ++j) {
        int t = w * 16 + (lane >> 4) * 4 + j;
        float wgt = (s <= t) ? __expf(Lsh[t0c + t] - Ls) * dts : 0.f;
        GWsh[t][s ^ ((t & 7) << 3)] = f2bf(Gacc[st][j] * wgt);
      }
    }
    __syncthreads();

    f32x4 Yacc[4], Y2acc[4];
    #pragma unroll
    for (int pt = 0; pt < 4; ++pt) { Yacc[pt] = (f32x4){0.f,0.f,0.f,0.f}; Y2acc[pt] = (f32x4){0.f,0.f,0.f,0.f}; }
    s16x8 aGW[2];
    #pragma unroll
    for (int k = 0; k < 2; ++k)
      aGW[k] = *(const s16x8*)&GWsh[w * 16 + (lane & 15)][(k * 32 + (lane >> 4) * 8) ^ swz];
    #pragma unroll
    for (int pt = 0; pt < 4; ++pt) {
      #pragma unroll
      for (int k = 0; k < 2; ++k) {
        s16x8 bX = *(const s16x8*)&Xt[pt * 16 + (lane & 15)][(k * 32 + (lane >> 4) * 8) ^ swz];
        Yacc[pt] = __builtin_amdgcn_mfma_f32_16x16x32_bf16(aGW[k], bX, Yacc[pt], 0, 0, 0);
      }
      #pragma unroll
      for (int k = 0; k < 4; ++k) {
        s16x8 bH = *(const s16x8*)&Hbf[pt * 16 + (lane & 15)][(k * 32 + (lane >> 4) * 8) ^ swz];
        Y2acc[pt] = __builtin_amdgcn_mfma_f32_16x16x32_bf16(aC[k], bH, Y2acc[pt], 0, 0, 0);
      }
    }
    float el[4];
    #pragma unroll
    for (int j = 0; j < 4; ++j) el[j] = __expf(Lsh[t0c + w * 16 + (lane >> 4) * 4 + j]);
    #pragma unroll
    for (int pt = 0; pt < 4; ++pt) {
      int p = pt * 16 + (lane & 15);
      #pragma unroll
      for (int j = 0; j < 4; ++j) {
        int t = w * 16 + (lane >> 4) * 4 + j;
        float xv = bf2f(Xt[p][t ^ ((p & 7) << 3)]);
        float yv = Yacc[pt][j] + el[j] * Y2acc[pt][j] + Dv * xv;
        y[((size_t)b * LSEQ + t0c + t) * DI + g * 512 + r * 64 + p] = yv;
      }
    }
    float e63 = __expf(Lsh[t0c + 63]);
    s16x8 aX[2];
    #pragma unroll
    for (int k = 0; k < 2; ++k)
      aX[k] = *(const s16x8*)&Xt[w * 16 + (lane & 15)][(k * 32 + (lane >> 4) * 8) ^ swz];
    #pragma unroll
    for (int nt = 0; nt < 8; ++nt) {
      #pragma unroll
      for (int j = 0; j < 4; ++j) hst[nt][j] *= e63;
      #pragma unroll
      for (int k = 0; k < 2; ++k) {
        s16x8 bW = *(const s16x8*)&Btw[nt * 16 + (lane & 15)][(k * 32 + (lane >> 4) * 8) ^ swz];
        hst[nt] = __builtin_amdgcn_mfma_f32_16x16x32_bf16(aX[k], bW, hst[nt], 0, 0, 0);
      }
    }
    __syncthreads();
    #pragma unroll
    for (int nt = 0; nt < 8; ++nt) {
      int n = nt * 16 + (lane & 15);
      #pragma unroll
      for (int j = 0; j < 4; ++j) {
        int p = w * 16 + (lane >> 4) * 4 + j;
        Hbf[p][n ^ ((p & 7) << 3)] = f2bf(hst[nt][j]);
      }
    }
  }
}

// ---------- y2 = rmsnorm(y * silu(z)) * gw -> bf16 ----------
__global__ __launch_bounds__(256) void gate_kernel(const float* __restrict__ y, const float* __restrict__ proj,
        const float* __restrict__ gw, u16* __restrict__ y2) {
  int row = blockIdx.x;
  const float* yr = y + (size_t)row * DI;
  const float* zr = proj + (size_t)row * PROJ_P;
  int tid = threadIdx.x;
  f32x4 v[4];
  float s = 0.f;
  #pragma unroll
  for (int i = 0; i < 4; i++) {
    int off = i * 1024 + tid * 4;
    f32x4 a = *(const f32x4*)&yr[off];
    f32x4 z = *(const f32x4*)&zr[off];
    f32x4 t;
    t.x = a.x * (z.x / (1.f + expf(-z.x)));
    t.y = a.y * (z.y / (1.f + expf(-z.y)));
    t.z = a.z * (z.z / (1.f + expf(-z.z)));
    t.w = a.w * (z.w / (1.f + expf(-z.w)));
    v[i] = t;
    s += t.x * t.x + t.y * t.y + t.z * t.z + t.w * t.w;
  }
  s = blockReduceSum256(s);
  float rs = rsqrtf(s * (1.f / DI) + 1e-5f);
  #pragma unroll
  for (int i = 0; i < 4; i++) {
    int off = i * 1024 + tid * 4;
    f32x4 wv = *(const f32x4*)&gw[off];
    u16x4 o;
    o.x = f2bf(v[i].x * rs * wv.x);
    o.y = f2bf(v[i].y * rs * wv.y);
    o.z = f2bf(v[i].z * rs * wv.z);
    o.w = f2bf(v[i].w * rs * wv.w);
    *(u16x4*)&y2[(size_t)row * DI + off] = o;
  }
}

extern "C" void kernel_launch(void* const* d_in, const int* in_sizes, int n_in,
                              void* d_out, int out_size, void* d_ws, size_t ws_size,
                              hipStream_t stream) {
  (void)in_sizes; (void)n_in; (void)out_size; (void)ws_size;
  const float* hs      = (const float*)d_in[0];
  const float* res     = (const float*)d_in[1];
  const float* norm_w  = (const float*)d_in[2];
  const float* w_in    = (const float*)d_in[3];
  const float* conv_w  = (const float*)d_in[4];
  const float* conv_b  = (const float*)d_in[5];
  const float* A_log   = (const float*)d_in[6];
  const float* D_param = (const float*)d_in[7];
  const float* dt_bias = (const float*)d_in[8];
  const float* gate_w  = (const float*)d_in[9];
  const float* w_out   = (const float*)d_in[10];

  float* out  = (float*)d_out;
  float* nres = out + (size_t)TOK * DM;

  char* ws = (char*)d_ws;
  size_t off = 0;
  u16*   WB1  = (u16*)(ws + off);   off += (size_t)PROJ_P * DM * 2;      // 43.0 MB
  u16*   WB2  = (u16*)(ws + off);   off += (size_t)DM * DI * 2;          // 16.8 MB
  u16*   XBF  = (u16*)(ws + off);   off += (size_t)TOK * DM * 2;         // 8.4 MB
  float* PROJ = (float*)(ws + off); off += (size_t)TOK * PROJ_P * 4;     // 86.0 MB
  u16*   XBC  = (u16*)(ws + off);   off += (size_t)TOK * CONV_D * 4;
  float* DTSP = (float*)(ws + off); off += (size_t)TOK * 64 * 4;
  float* DTA  = (float*)(ws + off); off += (size_t)TOK * 64 * 4;
  float* Y    = (float*)(ws + off); off += (size_t)TOK * DI * 4;         // 33.6 MB
  u16*   Y2   = (u16*)(ws + off);   off += (size_t)TOK * DI * 2;         // 16.8 MB

  // weight conversions
  cvt_bf16_pad<<<20992, 256, 0, stream>>>(w_in, WB1, (long)PROJ_D * DM, (long)PROJ_P * DM);
  cvt_bf16_pad<<<8192, 256, 0, stream>>>(w_out, WB2, (long)DM * DI, (long)DM * DI);
  // residual add + rmsnorm
  addnorm_kernel<<<TOK, 256, 0, stream>>>(hs, res, norm_w, nres, XBF);
  // in_proj GEMM: (2048 x 2048) x (10496 x 2048)^T -> 2048 x 10496, 256^2 pipelined
  gemm256<<<(PROJ_P / 256) * (TOK / 256), 512, 0, stream>>>(XBF, WB1, PROJ, DM, PROJ_P, PROJ_P / 256);
  // conv + silu on xBC slice -> bf16
  conv_silu_kernel<<<(TOK * (CONV_D / 4)) / 256, 256, 0, stream>>>(PROJ, conv_w, conv_b, XBC);
  // dt softplus + log-decay (transposed layout)
  dt_kernel<<<(TOK * 64) / 256, 256, 0, stream>>>(PROJ, dt_bias, A_log, DTSP, DTA);
  // chunked SSD scan (+ D*xs): 128 blocks = (b,h)
  ssd_kernel<<<128, 256, 0, stream>>>(XBC, DTSP, DTA, D_param, Y);
  // gated rmsnorm -> bf16
  gate_kernel<<<TOK, 256, 0, stream>>>(Y, PROJ, gate_w, Y2);
  // out_proj GEMM: (2048 x 4096) x (2048 x 4096)^T -> 2048 x 2048
  gemm_bt<<<dim3(DM / 128, TOK / 128), 256, 0, stream>>>(Y2, WB2, out, DI, DM);
}

// Round 6
// 403.770 us; speedup vs baseline: 2.2498x; 1.0833x over previous
//
#include <hip/hip_runtime.h>

#define TOK 2048
#define DM 2048
#define DI 4096
#define NG 8
#define NN 128
#define PROJ_D 10304
#define PROJ_P 10496
#define CONV_D 6144
#define LSEQ 1024
#define CHUNK 64
#define NCHUNK 16

typedef unsigned short u16;
typedef __attribute__((ext_vector_type(4))) float f32x4;
typedef __attribute__((ext_vector_type(8))) short s16x8;
typedef __attribute__((ext_vector_type(4))) unsigned short u16x4;

__device__ __forceinline__ u16 f2bf(float f) {
  union { float f; unsigned u; } x; x.f = f;
  unsigned r = (x.u + 0x7FFFu + ((x.u >> 16) & 1u)) >> 16;
  return (u16)r;
}
__device__ __forceinline__ float bf2f(u16 u) {
  union { unsigned u; float f; } x; x.u = ((unsigned)u) << 16; return x.f;
}

__device__ __forceinline__ float blockReduceSum256(float s) {
  __shared__ float red[4];
  #pragma unroll
  for (int o = 32; o > 0; o >>= 1) s += __shfl_down(s, o, 64);
  int lane = threadIdx.x & 63, wid = threadIdx.x >> 6;
  if (lane == 0) red[wid] = s;
  __syncthreads();
  return red[0] + red[1] + red[2] + red[3];
}

// ---------- fp32 -> bf16 weight conversion with zero padding ----------
__global__ __launch_bounds__(256) void cvt_bf16_pad(const float* __restrict__ src, u16* __restrict__ dst,
                                                    long n_src, long n_dst) {
  long i = ((long)blockIdx.x * 256 + threadIdx.x) * 4;
  if (i >= n_dst) return;
  u16x4 o;
  if (i < n_src) {
    f32x4 v = *(const f32x4*)&src[i];
    o.x = f2bf(v.x); o.y = f2bf(v.y); o.z = f2bf(v.z); o.w = f2bf(v.w);
  } else {
    o.x = 0; o.y = 0; o.z = 0; o.w = 0;
  }
  *(u16x4*)&dst[i] = o;
}

// ---------- h = hs + residual; new_residual = h; x = rmsnorm(h)*w -> bf16 ----------
__global__ __launch_bounds__(256) void addnorm_kernel(const float* __restrict__ hs, const float* __restrict__ res,
        const float* __restrict__ w, float* __restrict__ nres, u16* __restrict__ xbf) {
  int row = blockIdx.x;
  size_t base = (size_t)row * DM;
  int tid = threadIdx.x;
  f32x4 h[2];
  float s = 0.f;
  #pragma unroll
  for (int i = 0; i < 2; i++) {
    int off = i * 1024 + tid * 4;
    f32x4 a = *(const f32x4*)&hs[base + off];
    f32x4 b = *(const f32x4*)&res[base + off];
    f32x4 v = a + b;
    h[i] = v;
    *(f32x4*)&nres[base + off] = v;
    s += v.x * v.x + v.y * v.y + v.z * v.z + v.w * v.w;
  }
  s = blockReduceSum256(s);
  float rs = rsqrtf(s * (1.f / DM) + 1e-5f);
  #pragma unroll
  for (int i = 0; i < 2; i++) {
    int off = i * 1024 + tid * 4;
    f32x4 wv = *(const f32x4*)&w[off];
    f32x4 v = h[i];
    u16x4 o;
    o.x = f2bf(v.x * rs * wv.x);
    o.y = f2bf(v.y * rs * wv.y);
    o.z = f2bf(v.z * rs * wv.z);
    o.w = f2bf(v.w * rs * wv.w);
    *(u16x4*)&xbf[base + off] = o;
  }
}

__device__ __forceinline__ void gld_lds16(const void* g, void* l) {
  __builtin_amdgcn_global_load_lds((const __attribute__((address_space(1))) void*)g,
                                   (__attribute__((address_space(3))) void*)l, 16, 0, 0);
}

// ---------- pipelined bf16 GEMM, C[m][n] = sum_k A[m][k]*B[n][k] ----------
// 64x64 per-wave tiles; consumer-group staging: each A/B 64-row half is staged only
// by the waves that read it, ALL of a wave's loads for tile kt+1 issue at iteration-kt
// start, counted vmcnt(NV) at iteration kt+1 start -> full-iteration latency cover.
// col^((row&7)<<3) swizzle both-sides (pre-swizzled global source, swizzled ds_read).
template <int BM, int BN>
__global__ __launch_bounds__((BM / 64) * (BN / 64) * 64, 2)
void gemm_pipe(const u16* __restrict__ A, const u16* __restrict__ Bw,
               float* __restrict__ C, int K, int Cstride, int nbx) {
  constexpr int WM = BM / 64, WN = BN / 64;
  constexpr int NA = 8 / WN;            // A gld_lds per wave per K-tile
  constexpr int NB = 8 / WM;            // B gld_lds per wave per K-tile
  constexpr int NV = NA + NB;
  __shared__ u16 As[2][BM][64];
  __shared__ u16 Bs[2][BN][64];
  int tid = threadIdx.x;
  int lane = tid & 63, w = tid >> 6;
  int wr = w / WN, wc = w % WN;
  int cpx = gridDim.x >> 3;             // grid must be a multiple of 8
  int bid = blockIdx.x;
  int lb = (bid & 7) * cpx + (bid >> 3);
  int by = lb / nbx, bx = lb - by * nbx;
  size_t m0 = (size_t)by * BM, n0 = (size_t)bx * BN;
  const u16* Ab = A + m0 * K;
  const u16* Bb = Bw + n0 * K;

  f32x4 acc[4][4];
  #pragma unroll
  for (int i = 0; i < 4; ++i)
    #pragma unroll
    for (int j = 0; j < 4; ++j) acc[i][j] = (f32x4){0.f, 0.f, 0.f, 0.f};

  int l3 = lane >> 3;
  int colsw = ((lane & 7) ^ l3) << 3;   // pre-swizzled source col (elems)
  int fr = lane & 15, fq = lane >> 4;
  int pc0 = (fq * 8) ^ ((fr & 7) << 3); // frag phys col, ks=0
  int pc1 = pc0 ^ 32;                   // ks=1

  auto STAGE = [&](int d, int kt) {
    #pragma unroll
    for (int j = 0; j < NA; ++j) {
      int row = wr * 64 + (wc * NA + j) * 8;        // A-half wr, staged by its WN consumers
      gld_lds16(Ab + (size_t)(row + l3) * K + kt * 64 + colsw, &As[d][row][0]);
    }
    #pragma unroll
    for (int j = 0; j < NB; ++j) {
      int row = wc * 64 + (wr * NB + j) * 8;        // B-half wc, staged by its WM consumers
      gld_lds16(Bb + (size_t)(row + l3) * K + kt * 64 + colsw, &Bs[d][row][0]);
    }
  };

  int nkt = K >> 6;
  STAGE(0, 0);
  for (int kt = 0; kt < nkt; ++kt) {
    int d = kt & 1, nd = d ^ 1;
    if (kt + 1 < nkt) {
      STAGE(nd, kt + 1);                            // issue next tile NOW; wait next iter
      if constexpr (NV == 6) asm volatile("s_waitcnt vmcnt(6)" ::: "memory");
      else                   asm volatile("s_waitcnt vmcnt(8)" ::: "memory");
    } else {
      asm volatile("s_waitcnt vmcnt(0)" ::: "memory");
    }
    __builtin_amdgcn_s_barrier();                   // tile kt ready for everyone
    s16x8 b[4][2];
    #pragma unroll
    for (int ni = 0; ni < 4; ++ni) {
      b[ni][0] = *(const s16x8*)&Bs[d][wc * 64 + ni * 16 + fr][pc0];
      b[ni][1] = *(const s16x8*)&Bs[d][wc * 64 + ni * 16 + fr][pc1];
    }
    // phase 0: mi = 0,1
    {
      s16x8 a[2][2];
      #pragma unroll
      for (int mi = 0; mi < 2; ++mi) {
        a[mi][0] = *(const s16x8*)&As[d][wr * 64 + mi * 16 + fr][pc0];
        a[mi][1] = *(const s16x8*)&As[d][wr * 64 + mi * 16 + fr][pc1];
      }
      __builtin_amdgcn_s_setprio(1);
      #pragma unroll
      for (int mi = 0; mi < 2; ++mi)
        #pragma unroll
        for (int ni = 0; ni < 4; ++ni) {
          acc[mi][ni] = __builtin_amdgcn_mfma_f32_16x16x32_bf16(a[mi][0], b[ni][0], acc[mi][ni], 0, 0, 0);
          acc[mi][ni] = __builtin_amdgcn_mfma_f32_16x16x32_bf16(a[mi][1], b[ni][1], acc[mi][ni], 0, 0, 0);
        }
      __builtin_amdgcn_s_setprio(0);
    }
    __builtin_amdgcn_s_barrier();
    // phase 1: mi = 2,3
    {
      s16x8 a[2][2];
      #pragma unroll
      for (int mi = 0; mi < 2; ++mi) {
        a[mi][0] = *(const s16x8*)&As[d][wr * 64 + (mi + 2) * 16 + fr][pc0];
        a[mi][1] = *(const s16x8*)&As[d][wr * 64 + (mi + 2) * 16 + fr][pc1];
      }
      __builtin_amdgcn_s_setprio(1);
      #pragma unroll
      for (int mi = 0; mi < 2; ++mi)
        #pragma unroll
        for (int ni = 0; ni < 4; ++ni) {
          acc[mi + 2][ni] = __builtin_amdgcn_mfma_f32_16x16x32_bf16(a[mi][0], b[ni][0], acc[mi + 2][ni], 0, 0, 0);
          acc[mi + 2][ni] = __builtin_amdgcn_mfma_f32_16x16x32_bf16(a[mi][1], b[ni][1], acc[mi + 2][ni], 0, 0, 0);
        }
      __builtin_amdgcn_s_setprio(0);
    }
    __builtin_amdgcn_s_barrier();                   // iteration end: buf d reads done
  }
  // ---- epilogue ----
  size_t crow0 = m0 + wr * 64 + fq * 4;
  size_t ccol0 = n0 + wc * 64 + fr;
  #pragma unroll
  for (int mi = 0; mi < 4; ++mi)
    #pragma unroll
    for (int ni = 0; ni < 4; ++ni)
      #pragma unroll
      for (int j = 0; j < 4; ++j)
        C[(crow0 + mi * 16 + j) * Cstride + ccol0 + ni * 16] = acc[mi][ni][j];
}

// ---------- causal depthwise conv(K=4) + bias + SiLU -> bf16 ----------
__global__ __launch_bounds__(256) void conv_silu_kernel(const float* __restrict__ proj,
        const float* __restrict__ cw, const float* __restrict__ cb, u16* __restrict__ xbc) {
  long gid = (long)blockIdx.x * 256 + threadIdx.x;
  int c4 = (int)(gid % 1536);
  long t = gid / 1536;
  int l = (int)(t & 1023);
  int c = c4 * 4;
  const float* base = proj + (size_t)t * PROJ_P + DI + c;
  f32x4 acc = *(const f32x4*)&cb[c];
  f32x4 w0 = *(const f32x4*)&cw[(c + 0) * 4];
  f32x4 w1 = *(const f32x4*)&cw[(c + 1) * 4];
  f32x4 w2 = *(const f32x4*)&cw[(c + 2) * 4];
  f32x4 w3 = *(const f32x4*)&cw[(c + 3) * 4];
  #pragma unroll
  for (int k = 0; k < 4; k++) {
    int ls = l - 3 + k;
    if (ls >= 0) {
      f32x4 v = *(const f32x4*)(base + ((long)(k - 3)) * PROJ_P);
      acc.x = fmaf(v.x, w0[k], acc.x);
      acc.y = fmaf(v.y, w1[k], acc.y);
      acc.z = fmaf(v.z, w2[k], acc.z);
      acc.w = fmaf(v.w, w3[k], acc.w);
    }
  }
  u16x4 o;
  o.x = f2bf(acc.x / (1.f + expf(-acc.x)));
  o.y = f2bf(acc.y / (1.f + expf(-acc.y)));
  o.z = f2bf(acc.z / (1.f + expf(-acc.z)));
  o.w = f2bf(acc.w / (1.f + expf(-acc.w)));
  *(u16x4*)&xbc[(size_t)t * CONV_D + c] = o;
}

// ---------- dt: softplus(dt+bias) and log-decay dt*A, TRANSPOSED [b*64+h][L] ----------
__global__ __launch_bounds__(256) void dt_kernel(const float* __restrict__ proj, const float* __restrict__ dt_bias,
        const float* __restrict__ A_log, float* __restrict__ dtspT, float* __restrict__ dtaT) {
  int idx = blockIdx.x * 256 + threadIdx.x;
  int t = idx >> 6, hh = idx & 63;
  int b = t >> 10, l = t & 1023;
  float dtv = proj[(size_t)t * PROJ_P + (DI + CONV_D) + hh] + dt_bias[hh];
  float sp = (dtv > 15.f) ? dtv : log1pf(expf(dtv));
  float Ah = -expf(A_log[hh]);
  size_t o = (size_t)(b * 64 + hh) * LSEQ + l;
  dtspT[o] = sp;
  dtaT[o] = sp * Ah;   // log(dA) exactly
}

// ---------- chunked SSD scan: one block per (b,h); 16 chunks of 64 steps via MFMA ----------
__global__ __launch_bounds__(256) void ssd_kernel(const u16* __restrict__ xbc, const float* __restrict__ dtsp,
        const float* __restrict__ dta, const float* __restrict__ Dp, float* __restrict__ y) {
  int bid = blockIdx.x;
  int g = bid & 7, b = (bid >> 3) & 1, r = bid >> 4;
  int h = g * 8 + r;
  int tid = threadIdx.x;
  int w = tid >> 6, lane = tid & 63;

  __shared__ u16 Bsh[64][128];
  __shared__ u16 Csh[64][128];
  __shared__ u16 Xt[64][64];
  __shared__ u16 Btw[128][64];
  __shared__ u16 GWsh[64][64];
  __shared__ u16 Hbf[64][128];
  __shared__ float dtsh[LSEQ];
  __shared__ float Lsh[LSEQ];

  const float* dtrow = dtsp + (size_t)(b * 64 + h) * LSEQ;
  const float* dtarow = dta + (size_t)(b * 64 + h) * LSEQ;
  { f32x4 v = *(const f32x4*)&dtrow[tid * 4]; *(f32x4*)&dtsh[tid * 4] = v; }
  for (int cc = w; cc < NCHUNK; cc += 4) {
    float a = dtarow[cc * 64 + lane];
    #pragma unroll
    for (int o = 1; o < 64; o <<= 1) { float t2 = __shfl_up(a, o, 64); if (lane >= o) a += t2; }
    Lsh[cc * 64 + lane] = a;
  }
  {
    u16* hp = &Hbf[0][0];
    for (int i = tid; i < 2048; i += 256) *(u16x4*)&hp[i * 4] = (u16x4){0, 0, 0, 0};
  }
  f32x4 hst[8];
  #pragma unroll
  for (int i = 0; i < 8; i++) hst[i] = (f32x4){0.f, 0.f, 0.f, 0.f};
  float Dv = Dp[h];
  const u16* xb = xbc + (size_t)b * LSEQ * CONV_D;
  int swz = (lane & 7) << 3;
  __syncthreads();

  for (int c = 0; c < NCHUNK; ++c) {
    int t0c = c * 64;
    #pragma unroll
    for (int q = 0; q < 4; ++q) {
      int rowb = w * 16 + q * 4;
      int row = rowb + (lane >> 4);
      int colb = ((lane & 15) * 8) ^ ((row & 7) << 3);
      gld_lds16(xb + (size_t)(t0c + row) * CONV_D + DI + g * 128 + colb, &Bsh[rowb][0]);
      gld_lds16(xb + (size_t)(t0c + row) * CONV_D + DI + NG * NN + g * 128 + colb, &Csh[rowb][0]);
    }
    {
      int s = tid & 63, pq = tid >> 6;
      const u16* xr = xb + (size_t)(t0c + s) * CONV_D + g * 512 + r * 64;
      #pragma unroll
      for (int pb = 0; pb < 4; ++pb) {
        int p0 = pb * 16 + pq * 4;
        u16x4 v = *(const u16x4*)&xr[p0];
        #pragma unroll
        for (int j = 0; j < 4; ++j) {
          int p = p0 + j;
          Xt[p][s ^ ((p & 7) << 3)] = v[j];
        }
      }
    }
    {
      int s = tid & 63, nq = tid >> 6;
      float wend = __expf(Lsh[t0c + 63] - Lsh[t0c + s]) * dtsh[t0c + s];
      const u16* br = xb + (size_t)(t0c + s) * CONV_D + DI + g * 128;
      #pragma unroll
      for (int nb = 0; nb < 8; ++nb) {
        int n0 = nb * 16 + nq * 4;
        u16x4 v = *(const u16x4*)&br[n0];
        #pragma unroll
        for (int j = 0; j < 4; ++j) {
          int n = n0 + j;
          Btw[n][s ^ ((n & 7) << 3)] = f2bf(bf2f(v[j]) * wend);
        }
      }
    }
    __syncthreads();

    s16x8 aC[4];
    #pragma unroll
    for (int k = 0; k < 4; ++k)
      aC[k] = *(const s16x8*)&Csh[w * 16 + (lane & 15)][(k * 32 + (lane >> 4) * 8) ^ swz];
    f32x4 Gacc[4];
    #pragma unroll
    for (int st = 0; st < 4; ++st) Gacc[st] = (f32x4){0.f, 0.f, 0.f, 0.f};
    #pragma unroll
    for (int st = 0; st < 4; ++st)
      #pragma unroll
      for (int k = 0; k < 4; ++k) {
        s16x8 bB = *(const s16x8*)&Bsh[st * 16 + (lane & 15)][(k * 32 + (lane >> 4) * 8) ^ swz];
        Gacc[st] = __builtin_amdgcn_mfma_f32_16x16x32_bf16(aC[k], bB, Gacc[st], 0, 0, 0);
      }
    #pragma unroll
    for (int st = 0; st < 4; ++st) {
      int s = st * 16 + (lane & 15);
      float Ls = Lsh[t0c + s], dts = dtsh[t0c + s];
      #pragma unroll
      for (int j = 0; j < 4; ++j) {
        int t = w * 16 + (lane >> 4) * 4 + j;
        float wgt = (s <= t) ? __expf(Lsh[t0c + t] - Ls) * dts : 0.f;
        GWsh[t][s ^ ((t & 7) << 3)] = f2bf(Gacc[st][j] * wgt);
      }
    }
    __syncthreads();

    f32x4 Yacc[4], Y2acc[4];
    #pragma unroll
    for (int pt = 0; pt < 4; ++pt) { Yacc[pt] = (f32x4){0.f,0.f,0.f,0.f}; Y2acc[pt] = (f32x4){0.f,0.f,0.f,0.f}; }
    s16x8 aGW[2];
    #pragma unroll
    for (int k = 0; k < 2; ++k)
      aGW[k] = *(const s16x8*)&GWsh[w * 16 + (lane & 15)][(k * 32 + (lane >> 4) * 8) ^ swz];
    #pragma unroll
    for (int pt = 0; pt < 4; ++pt) {
      #pragma unroll
      for (int k = 0; k < 2; ++k) {
        s16x8 bX = *(const s16x8*)&Xt[pt * 16 + (lane & 15)][(k * 32 + (lane >> 4) * 8) ^ swz];
        Yacc[pt] = __builtin_amdgcn_mfma_f32_16x16x32_bf16(aGW[k], bX, Yacc[pt], 0, 0, 0);
      }
      #pragma unroll
      for (int k = 0; k < 4; ++k) {
        s16x8 bH = *(const s16x8*)&Hbf[pt * 16 + (lane & 15)][(k * 32 + (lane >> 4) * 8) ^ swz];
        Y2acc[pt] = __builtin_amdgcn_mfma_f32_16x16x32_bf16(aC[k], bH, Y2acc[pt], 0, 0, 0);
      }
    }
    float el[4];
    #pragma unroll
    for (int j = 0; j < 4; ++j) el[j] = __expf(Lsh[t0c + w * 16 + (lane >> 4) * 4 + j]);
    #pragma unroll
    for (int pt = 0; pt < 4; ++pt) {
      int p = pt * 16 + (lane & 15);
      #pragma unroll
      for (int j = 0; j < 4; ++j) {
        int t = w * 16 + (lane >> 4) * 4 + j;
        float xv = bf2f(Xt[p][t ^ ((p & 7) << 3)]);
        float yv = Yacc[pt][j] + el[j] * Y2acc[pt][j] + Dv * xv;
        y[((size_t)b * LSEQ + t0c + t) * DI + g * 512 + r * 64 + p] = yv;
      }
    }
    float e63 = __expf(Lsh[t0c + 63]);
    s16x8 aX[2];
    #pragma unroll
    for (int k = 0; k < 2; ++k)
      aX[k] = *(const s16x8*)&Xt[w * 16 + (lane & 15)][(k * 32 + (lane >> 4) * 8) ^ swz];
    #pragma unroll
    for (int nt = 0; nt < 8; ++nt) {
      #pragma unroll
      for (int j = 0; j < 4; ++j) hst[nt][j] *= e63;
      #pragma unroll
      for (int k = 0; k < 2; ++k) {
        s16x8 bW = *(const s16x8*)&Btw[nt * 16 + (lane & 15)][(k * 32 + (lane >> 4) * 8) ^ swz];
        hst[nt] = __builtin_amdgcn_mfma_f32_16x16x32_bf16(aX[k], bW, hst[nt], 0, 0, 0);
      }
    }
    __syncthreads();
    #pragma unroll
    for (int nt = 0; nt < 8; ++nt) {
      int n = nt * 16 + (lane & 15);
      #pragma unroll
      for (int j = 0; j < 4; ++j) {
        int p = w * 16 + (lane >> 4) * 4 + j;
        Hbf[p][n ^ ((p & 7) << 3)] = f2bf(hst[nt][j]);
      }
    }
  }
}

// ---------- y2 = rmsnorm(y * silu(z)) * gw -> bf16 ----------
__global__ __launch_bounds__(256) void gate_kernel(const float* __restrict__ y, const float* __restrict__ proj,
        const float* __restrict__ gw, u16* __restrict__ y2) {
  int row = blockIdx.x;
  const float* yr = y + (size_t)row * DI;
  const float* zr = proj + (size_t)row * PROJ_P;
  int tid = threadIdx.x;
  f32x4 v[4];
  float s = 0.f;
  #pragma unroll
  for (int i = 0; i < 4; i++) {
    int off = i * 1024 + tid * 4;
    f32x4 a = *(const f32x4*)&yr[off];
    f32x4 z = *(const f32x4*)&zr[off];
    f32x4 t;
    t.x = a.x * (z.x / (1.f + expf(-z.x)));
    t.y = a.y * (z.y / (1.f + expf(-z.y)));
    t.z = a.z * (z.z / (1.f + expf(-z.z)));
    t.w = a.w * (z.w / (1.f + expf(-z.w)));
    v[i] = t;
    s += t.x * t.x + t.y * t.y + t.z * t.z + t.w * t.w;
  }
  s = blockReduceSum256(s);
  float rs = rsqrtf(s * (1.f / DI) + 1e-5f);
  #pragma unroll
  for (int i = 0; i < 4; i++) {
    int off = i * 1024 + tid * 4;
    f32x4 wv = *(const f32x4*)&gw[off];
    u16x4 o;
    o.x = f2bf(v[i].x * rs * wv.x);
    o.y = f2bf(v[i].y * rs * wv.y);
    o.z = f2bf(v[i].z * rs * wv.z);
    o.w = f2bf(v[i].w * rs * wv.w);
    *(u16x4*)&y2[(size_t)row * DI + off] = o;
  }
}

extern "C" void kernel_launch(void* const* d_in, const int* in_sizes, int n_in,
                              void* d_out, int out_size, void* d_ws, size_t ws_size,
                              hipStream_t stream) {
  (void)in_sizes; (void)n_in; (void)out_size; (void)ws_size;
  const float* hs      = (const float*)d_in[0];
  const float* res     = (const float*)d_in[1];
  const float* norm_w  = (const float*)d_in[2];
  const float* w_in    = (const float*)d_in[3];
  const float* conv_w  = (const float*)d_in[4];
  const float* conv_b  = (const float*)d_in[5];
  const float* A_log   = (const float*)d_in[6];
  const float* D_param = (const float*)d_in[7];
  const float* dt_bias = (const float*)d_in[8];
  const float* gate_w  = (const float*)d_in[9];
  const float* w_out   = (const float*)d_in[10];

  float* out  = (float*)d_out;
  float* nres = out + (size_t)TOK * DM;

  char* ws = (char*)d_ws;
  size_t off = 0;
  u16*   WB1  = (u16*)(ws + off);   off += (size_t)PROJ_P * DM * 2;      // 43.0 MB
  u16*   WB2  = (u16*)(ws + off);   off += (size_t)DM * DI * 2;          // 16.8 MB
  u16*   XBF  = (u16*)(ws + off);   off += (size_t)TOK * DM * 2;         // 8.4 MB
  float* PROJ = (float*)(ws + off); off += (size_t)TOK * PROJ_P * 4;     // 86.0 MB
  u16*   XBC  = (u16*)(ws + off);   off += (size_t)TOK * CONV_D * 4;
  float* DTSP = (float*)(ws + off); off += (size_t)TOK * 64 * 4;
  float* DTA  = (float*)(ws + off); off += (size_t)TOK * 64 * 4;
  float* Y    = (float*)(ws + off); off += (size_t)TOK * DI * 4;         // 33.6 MB
  u16*   Y2   = (u16*)(ws + off);   off += (size_t)TOK * DI * 2;         // 16.8 MB

  // weight conversions
  cvt_bf16_pad<<<20992, 256, 0, stream>>>(w_in, WB1, (long)PROJ_D * DM, (long)PROJ_P * DM);
  cvt_bf16_pad<<<8192, 256, 0, stream>>>(w_out, WB2, (long)DM * DI, (long)DM * DI);
  // residual add + rmsnorm
  addnorm_kernel<<<TOK, 256, 0, stream>>>(hs, res, norm_w, nres, XBF);
  // in_proj GEMM: (2048 x 2048) x (10496 x 2048)^T -> 2048 x 10496
  gemm_pipe<128, 256><<<(TOK / 128) * (PROJ_P / 256), 512, 0, stream>>>(XBF, WB1, PROJ, DM, PROJ_P, PROJ_P / 256);
  // conv + silu on xBC slice -> bf16
  conv_silu_kernel<<<(TOK * (CONV_D / 4)) / 256, 256, 0, stream>>>(PROJ, conv_w, conv_b, XBC);
  // dt softplus + log-decay (transposed layout)
  dt_kernel<<<(TOK * 64) / 256, 256, 0, stream>>>(PROJ, dt_bias, A_log, DTSP, DTA);
  // chunked SSD scan (+ D*xs): 128 blocks = (b,h)
  ssd_kernel<<<128, 256, 0, stream>>>(XBC, DTSP, DTA, D_param, Y);
  // gated rmsnorm -> bf16
  gate_kernel<<<TOK, 256, 0, stream>>>(Y, PROJ, gate_w, Y2);
  // out_proj GEMM: (2048 x 4096) x (2048 x 4096)^T -> 2048 x 2048, grid = 256 = 1/CU
  gemm_pipe<128, 128><<<(TOK / 128) * (DM / 128), 256, 0, stream>>>(Y2, WB2, out, DI, DM, DM / 128);
}

// Round 7
// 375.264 us; speedup vs baseline: 2.4207x; 1.0760x over previous
//
#include <hip/hip_runtime.h>

#define TOK 2048
#define DM 2048
#define DI 4096
#define NG 8
#define NN 128
#define PROJ_D 10304
#define PROJ_P 10496
#define CONV_D 6144
#define LSEQ 1024
#define CHUNK 64
#define NCHUNK 16

typedef unsigned short u16;
typedef __attribute__((ext_vector_type(4))) float f32x4;
typedef __attribute__((ext_vector_type(8))) short s16x8;
typedef __attribute__((ext_vector_type(4))) unsigned short u16x4;

__device__ __forceinline__ u16 f2bf(float f) {
  union { float f; unsigned u; } x; x.f = f;
  unsigned r = (x.u + 0x7FFFu + ((x.u >> 16) & 1u)) >> 16;
  return (u16)r;
}
__device__ __forceinline__ float bf2f(u16 u) {
  union { unsigned u; float f; } x; x.u = ((unsigned)u) << 16; return x.f;
}

__device__ __forceinline__ float blockReduceSum256(float s) {
  __shared__ float red[4];
  #pragma unroll
  for (int o = 32; o > 0; o >>= 1) s += __shfl_down(s, o, 64);
  int lane = threadIdx.x & 63, wid = threadIdx.x >> 6;
  if (lane == 0) red[wid] = s;
  __syncthreads();
  return red[0] + red[1] + red[2] + red[3];
}

// ---------- fp32 -> bf16 weight conversion with zero padding ----------
__global__ __launch_bounds__(256) void cvt_bf16_pad(const float* __restrict__ src, u16* __restrict__ dst,
                                                    long n_src, long n_dst) {
  long i = ((long)blockIdx.x * 256 + threadIdx.x) * 4;
  if (i >= n_dst) return;
  u16x4 o;
  if (i < n_src) {
    f32x4 v = *(const f32x4*)&src[i];
    o.x = f2bf(v.x); o.y = f2bf(v.y); o.z = f2bf(v.z); o.w = f2bf(v.w);
  } else {
    o.x = 0; o.y = 0; o.z = 0; o.w = 0;
  }
  *(u16x4*)&dst[i] = o;
}

// ---------- h = hs + residual; new_residual = h; x = rmsnorm(h)*w -> bf16 ----------
__global__ __launch_bounds__(256) void addnorm_kernel(const float* __restrict__ hs, const float* __restrict__ res,
        const float* __restrict__ w, float* __restrict__ nres, u16* __restrict__ xbf) {
  int row = blockIdx.x;
  size_t base = (size_t)row * DM;
  int tid = threadIdx.x;
  f32x4 h[2];
  float s = 0.f;
  #pragma unroll
  for (int i = 0; i < 2; i++) {
    int off = i * 1024 + tid * 4;
    f32x4 a = *(const f32x4*)&hs[base + off];
    f32x4 b = *(const f32x4*)&res[base + off];
    f32x4 v = a + b;
    h[i] = v;
    *(f32x4*)&nres[base + off] = v;
    s += v.x * v.x + v.y * v.y + v.z * v.z + v.w * v.w;
  }
  s = blockReduceSum256(s);
  float rs = rsqrtf(s * (1.f / DM) + 1e-5f);
  #pragma unroll
  for (int i = 0; i < 2; i++) {
    int off = i * 1024 + tid * 4;
    f32x4 wv = *(const f32x4*)&w[off];
    f32x4 v = h[i];
    u16x4 o;
    o.x = f2bf(v.x * rs * wv.x);
    o.y = f2bf(v.y * rs * wv.y);
    o.z = f2bf(v.z * rs * wv.z);
    o.w = f2bf(v.w * rs * wv.w);
    *(u16x4*)&xbf[base + off] = o;
  }
}

__device__ __forceinline__ void gld_lds16(const void* g, void* l) {
  __builtin_amdgcn_global_load_lds((const __attribute__((address_space(1))) void*)g,
                                   (__attribute__((address_space(3))) void*)l, 16, 0, 0);
}

// ---------- 256x256 8-phase bf16 GEMM (m201-style), C[m][n] = sum_k A[m][k]*B[n][k] ----------
// 8 waves (2Mx4N), per-wave C = 128x64, BK=64, LDS 128 KiB dbuf.
// Phase q of K-tile kt: {ds-load frags (12 at q0, 4 else) | stage 1 half-tile |
//   [q3: counted vmcnt(4)] | barrier | setprio(1) 16 MFMA setprio(0) | barrier}.
// Stage schedule: q0:(kt+1).A0  q1:(kt+1).A1  q2:(kt+2).B0  q3:(kt+2).B1.
// Ledger: vmcnt(4) at q3 keeps kt+2's B halves in flight, retires kt+1's A halves
// (issued 2-3 phases earlier). Write-after-read separated by >=1 barrier:
// B-region of buf d is only register-read at q0 (stage at q2/q3); kt+1 halves go
// to the idle buffer; A-quadrant q is read at phase q, overwritten next K-tile.
__global__ __launch_bounds__(512, 2) void gemm8p(const u16* __restrict__ A, const u16* __restrict__ Bw,
                                                 float* __restrict__ C, int K, int Cstride, int nbx) {
  __shared__ u16 As[2][256][64];
  __shared__ u16 Bs[2][256][64];
  int tid = threadIdx.x;
  int lane = tid & 63, w = tid >> 6;
  int wr = w >> 2, wc = w & 3;
  int cpx = gridDim.x >> 3;                 // grid must be a multiple of 8
  int bid = blockIdx.x;
  int lb = (bid & 7) * cpx + (bid >> 3);    // bijective XCD swizzle
  int by = lb / nbx, bx = lb - by * nbx;
  size_t m0 = (size_t)by * 256, n0 = (size_t)bx * 256;
  const u16* Ab = A + m0 * K;
  const u16* Bb = Bw + n0 * K;

  f32x4 acc[8][4];
  #pragma unroll
  for (int i = 0; i < 8; ++i)
    #pragma unroll
    for (int j = 0; j < 4; ++j) acc[i][j] = (f32x4){0.f, 0.f, 0.f, 0.f};

  int l3 = lane >> 3;
  int colsw = ((lane & 7) ^ l3) << 3;       // pre-swizzled global source col
  int fr = lane & 15, fq = lane >> 4;
  int pc0 = (fq * 8) ^ ((fr & 7) << 3);     // frag phys col, ks=0
  int pc1 = pc0 ^ 32;                       // ks=1

  // stage one half-tile (128 rows): mat 0=A,1=B; 2 gld_lds16 per wave
  auto S = [&](int kt, int mat, int half) {
    int d = kt & 1;
    const u16* src = mat ? Bb : Ab;
    u16* dstbase = mat ? &Bs[d][0][0] : &As[d][0][0];
    #pragma unroll
    for (int j = 0; j < 2; ++j) {
      int rb = half * 128 + (w * 2 + j) * 8;
      gld_lds16(src + (size_t)(rb + l3) * K + kt * 64 + colsw, dstbase + rb * 64);
    }
  };

  int nkt = K >> 6;                          // requires nkt >= 2
  // prologue: kt0 all 4 halves + kt1 B halves; retire kt0 (keep kt1.B in flight)
  S(0, 1, 0); S(0, 1, 1); S(0, 0, 0); S(0, 0, 1);
  S(1, 1, 0); S(1, 1, 1);
  asm volatile("s_waitcnt vmcnt(4)" ::: "memory");
  __builtin_amdgcn_s_barrier();

  for (int kt = 0; kt < nkt; ++kt) {
    int d = kt & 1;
    s16x8 b[4][2];
    #pragma unroll
    for (int q = 0; q < 4; ++q) {
      if (q == 0) {
        #pragma unroll
        for (int ni = 0; ni < 4; ++ni) {
          b[ni][0] = *(const s16x8*)&Bs[d][wc * 64 + ni * 16 + fr][pc0];
          b[ni][1] = *(const s16x8*)&Bs[d][wc * 64 + ni * 16 + fr][pc1];
        }
      }
      s16x8 a[2][2];
      #pragma unroll
      for (int mi = 0; mi < 2; ++mi) {
        a[mi][0] = *(const s16x8*)&As[d][wr * 128 + q * 32 + mi * 16 + fr][pc0];
        a[mi][1] = *(const s16x8*)&As[d][wr * 128 + q * 32 + mi * 16 + fr][pc1];
      }
      if (q == 0)      { if (kt + 1 < nkt) S(kt + 1, 0, 0); }
      else if (q == 1) { if (kt + 1 < nkt) S(kt + 1, 0, 1); }
      else if (q == 2) { if (kt + 2 < nkt) S(kt + 2, 1, 0); }
      else {
        if (kt + 2 < nkt) { S(kt + 2, 1, 1); asm volatile("s_waitcnt vmcnt(4)" ::: "memory"); }
        else              { asm volatile("s_waitcnt vmcnt(0)" ::: "memory"); }
      }
      __builtin_amdgcn_s_barrier();
      __builtin_amdgcn_s_setprio(1);
      #pragma unroll
      for (int mi = 0; mi < 2; ++mi)
        #pragma unroll
        for (int ni = 0; ni < 4; ++ni) {
          acc[q * 2 + mi][ni] = __builtin_amdgcn_mfma_f32_16x16x32_bf16(a[mi][0], b[ni][0], acc[q * 2 + mi][ni], 0, 0, 0);
          acc[q * 2 + mi][ni] = __builtin_amdgcn_mfma_f32_16x16x32_bf16(a[mi][1], b[ni][1], acc[q * 2 + mi][ni], 0, 0, 0);
        }
      __builtin_amdgcn_s_setprio(0);
      __builtin_amdgcn_s_barrier();
    }
  }
  // epilogue
  size_t crow0 = m0 + wr * 128 + fq * 4;
  size_t ccol0 = n0 + wc * 64 + fr;
  #pragma unroll
  for (int mf = 0; mf < 8; ++mf)
    #pragma unroll
    for (int ni = 0; ni < 4; ++ni)
      #pragma unroll
      for (int j = 0; j < 4; ++j)
        C[(crow0 + mf * 16 + j) * Cstride + ccol0 + ni * 16] = acc[mf][ni][j];
}

// ---------- pipelined bf16 GEMM (R5 structure, kept for out_proj; grid=256=1/CU) ----------
template <int BM, int BN>
__global__ __launch_bounds__((BM / 64) * (BN / 64) * 64, 2)
void gemm_pipe(const u16* __restrict__ A, const u16* __restrict__ Bw,
               float* __restrict__ C, int K, int Cstride, int nbx) {
  constexpr int WM = BM / 64, WN = BN / 64;
  constexpr int NA = 8 / WN;
  constexpr int NB = 8 / WM;
  constexpr int NV = NA + NB;
  __shared__ u16 As[2][BM][64];
  __shared__ u16 Bs[2][BN][64];
  int tid = threadIdx.x;
  int lane = tid & 63, w = tid >> 6;
  int wr = w / WN, wc = w % WN;
  int cpx = gridDim.x >> 3;
  int bid = blockIdx.x;
  int lb = (bid & 7) * cpx + (bid >> 3);
  int by = lb / nbx, bx = lb - by * nbx;
  size_t m0 = (size_t)by * BM, n0 = (size_t)bx * BN;
  const u16* Ab = A + m0 * K;
  const u16* Bb = Bw + n0 * K;

  f32x4 acc[4][4];
  #pragma unroll
  for (int i = 0; i < 4; ++i)
    #pragma unroll
    for (int j = 0; j < 4; ++j) acc[i][j] = (f32x4){0.f, 0.f, 0.f, 0.f};

  int l3 = lane >> 3;
  int colsw = ((lane & 7) ^ l3) << 3;
  int fr = lane & 15, fq = lane >> 4;
  int pc0 = (fq * 8) ^ ((fr & 7) << 3);
  int pc1 = pc0 ^ 32;

  auto STAGE = [&](int d, int kt) {
    #pragma unroll
    for (int j = 0; j < NA; ++j) {
      int row = wr * 64 + (wc * NA + j) * 8;
      gld_lds16(Ab + (size_t)(row + l3) * K + kt * 64 + colsw, &As[d][row][0]);
    }
    #pragma unroll
    for (int j = 0; j < NB; ++j) {
      int row = wc * 64 + (wr * NB + j) * 8;
      gld_lds16(Bb + (size_t)(row + l3) * K + kt * 64 + colsw, &Bs[d][row][0]);
    }
  };

  int nkt = K >> 6;
  STAGE(0, 0);
  for (int kt = 0; kt < nkt; ++kt) {
    int d = kt & 1, nd = d ^ 1;
    if (kt + 1 < nkt) {
      STAGE(nd, kt + 1);
      if constexpr (NV == 6) asm volatile("s_waitcnt vmcnt(6)" ::: "memory");
      else                   asm volatile("s_waitcnt vmcnt(8)" ::: "memory");
    } else {
      asm volatile("s_waitcnt vmcnt(0)" ::: "memory");
    }
    __builtin_amdgcn_s_barrier();
    s16x8 b[4][2];
    #pragma unroll
    for (int ni = 0; ni < 4; ++ni) {
      b[ni][0] = *(const s16x8*)&Bs[d][wc * 64 + ni * 16 + fr][pc0];
      b[ni][1] = *(const s16x8*)&Bs[d][wc * 64 + ni * 16 + fr][pc1];
    }
    {
      s16x8 a[2][2];
      #pragma unroll
      for (int mi = 0; mi < 2; ++mi) {
        a[mi][0] = *(const s16x8*)&As[d][wr * 64 + mi * 16 + fr][pc0];
        a[mi][1] = *(const s16x8*)&As[d][wr * 64 + mi * 16 + fr][pc1];
      }
      __builtin_amdgcn_s_setprio(1);
      #pragma unroll
      for (int mi = 0; mi < 2; ++mi)
        #pragma unroll
        for (int ni = 0; ni < 4; ++ni) {
          acc[mi][ni] = __builtin_amdgcn_mfma_f32_16x16x32_bf16(a[mi][0], b[ni][0], acc[mi][ni], 0, 0, 0);
          acc[mi][ni] = __builtin_amdgcn_mfma_f32_16x16x32_bf16(a[mi][1], b[ni][1], acc[mi][ni], 0, 0, 0);
        }
      __builtin_amdgcn_s_setprio(0);
    }
    __builtin_amdgcn_s_barrier();
    {
      s16x8 a[2][2];
      #pragma unroll
      for (int mi = 0; mi < 2; ++mi) {
        a[mi][0] = *(const s16x8*)&As[d][wr * 64 + (mi + 2) * 16 + fr][pc0];
        a[mi][1] = *(const s16x8*)&As[d][wr * 64 + (mi + 2) * 16 + fr][pc1];
      }
      __builtin_amdgcn_s_setprio(1);
      #pragma unroll
      for (int mi = 0; mi < 2; ++mi)
        #pragma unroll
        for (int ni = 0; ni < 4; ++ni) {
          acc[mi + 2][ni] = __builtin_amdgcn_mfma_f32_16x16x32_bf16(a[mi][0], b[ni][0], acc[mi + 2][ni], 0, 0, 0);
          acc[mi + 2][ni] = __builtin_amdgcn_mfma_f32_16x16x32_bf16(a[mi][1], b[ni][1], acc[mi + 2][ni], 0, 0, 0);
        }
      __builtin_amdgcn_s_setprio(0);
    }
    __builtin_amdgcn_s_barrier();
  }
  size_t crow0 = m0 + wr * 64 + fq * 4;
  size_t ccol0 = n0 + wc * 64 + fr;
  #pragma unroll
  for (int mi = 0; mi < 4; ++mi)
    #pragma unroll
    for (int ni = 0; ni < 4; ++ni)
      #pragma unroll
      for (int j = 0; j < 4; ++j)
        C[(crow0 + mi * 16 + j) * Cstride + ccol0 + ni * 16] = acc[mi][ni][j];
}

// ---------- causal depthwise conv(K=4) + bias + SiLU -> bf16 ----------
__global__ __launch_bounds__(256) void conv_silu_kernel(const float* __restrict__ proj,
        const float* __restrict__ cw, const float* __restrict__ cb, u16* __restrict__ xbc) {
  long gid = (long)blockIdx.x * 256 + threadIdx.x;
  int c4 = (int)(gid % 1536);
  long t = gid / 1536;
  int l = (int)(t & 1023);
  int c = c4 * 4;
  const float* base = proj + (size_t)t * PROJ_P + DI + c;
  f32x4 acc = *(const f32x4*)&cb[c];
  f32x4 w0 = *(const f32x4*)&cw[(c + 0) * 4];
  f32x4 w1 = *(const f32x4*)&cw[(c + 1) * 4];
  f32x4 w2 = *(const f32x4*)&cw[(c + 2) * 4];
  f32x4 w3 = *(const f32x4*)&cw[(c + 3) * 4];
  #pragma unroll
  for (int k = 0; k < 4; k++) {
    int ls = l - 3 + k;
    if (ls >= 0) {
      f32x4 v = *(const f32x4*)(base + ((long)(k - 3)) * PROJ_P);
      acc.x = fmaf(v.x, w0[k], acc.x);
      acc.y = fmaf(v.y, w1[k], acc.y);
      acc.z = fmaf(v.z, w2[k], acc.z);
      acc.w = fmaf(v.w, w3[k], acc.w);
    }
  }
  u16x4 o;
  o.x = f2bf(acc.x / (1.f + expf(-acc.x)));
  o.y = f2bf(acc.y / (1.f + expf(-acc.y)));
  o.z = f2bf(acc.z / (1.f + expf(-acc.z)));
  o.w = f2bf(acc.w / (1.f + expf(-acc.w)));
  *(u16x4*)&xbc[(size_t)t * CONV_D + c] = o;
}

// ---------- dt: softplus(dt+bias) and log-decay dt*A, TRANSPOSED [b*64+h][L] ----------
__global__ __launch_bounds__(256) void dt_kernel(const float* __restrict__ proj, const float* __restrict__ dt_bias,
        const float* __restrict__ A_log, float* __restrict__ dtspT, float* __restrict__ dtaT) {
  int idx = blockIdx.x * 256 + threadIdx.x;
  int t = idx >> 6, hh = idx & 63;
  int b = t >> 10, l = t & 1023;
  float dtv = proj[(size_t)t * PROJ_P + (DI + CONV_D) + hh] + dt_bias[hh];
  float sp = (dtv > 15.f) ? dtv : log1pf(expf(dtv));
  float Ah = -expf(A_log[hh]);
  size_t o = (size_t)(b * 64 + hh) * LSEQ + l;
  dtspT[o] = sp;
  dtaT[o] = sp * Ah;   // log(dA) exactly
}

// ---------- chunked SSD scan: one block per (b,h); 16 chunks of 64 steps via MFMA ----------
__global__ __launch_bounds__(256) void ssd_kernel(const u16* __restrict__ xbc, const float* __restrict__ dtsp,
        const float* __restrict__ dta, const float* __restrict__ Dp, float* __restrict__ y) {
  int bid = blockIdx.x;
  int g = bid & 7, b = (bid >> 3) & 1, r = bid >> 4;
  int h = g * 8 + r;
  int tid = threadIdx.x;
  int w = tid >> 6, lane = tid & 63;

  __shared__ u16 Bsh[64][128];
  __shared__ u16 Csh[64][128];
  __shared__ u16 Xt[64][64];
  __shared__ u16 Btw[128][64];
  __shared__ u16 GWsh[64][64];
  __shared__ u16 Hbf[64][128];
  __shared__ float dtsh[LSEQ];
  __shared__ float Lsh[LSEQ];

  const float* dtrow = dtsp + (size_t)(b * 64 + h) * LSEQ;
  const float* dtarow = dta + (size_t)(b * 64 + h) * LSEQ;
  { f32x4 v = *(const f32x4*)&dtrow[tid * 4]; *(f32x4*)&dtsh[tid * 4] = v; }
  for (int cc = w; cc < NCHUNK; cc += 4) {
    float a = dtarow[cc * 64 + lane];
    #pragma unroll
    for (int o = 1; o < 64; o <<= 1) { float t2 = __shfl_up(a, o, 64); if (lane >= o) a += t2; }
    Lsh[cc * 64 + lane] = a;
  }
  {
    u16* hp = &Hbf[0][0];
    for (int i = tid; i < 2048; i += 256) *(u16x4*)&hp[i * 4] = (u16x4){0, 0, 0, 0};
  }
  f32x4 hst[8];
  #pragma unroll
  for (int i = 0; i < 8; i++) hst[i] = (f32x4){0.f, 0.f, 0.f, 0.f};
  float Dv = Dp[h];
  const u16* xb = xbc + (size_t)b * LSEQ * CONV_D;
  int swz = (lane & 7) << 3;
  __syncthreads();

  for (int c = 0; c < NCHUNK; ++c) {
    int t0c = c * 64;
    #pragma unroll
    for (int q = 0; q < 4; ++q) {
      int rowb = w * 16 + q * 4;
      int row = rowb + (lane >> 4);
      int colb = ((lane & 15) * 8) ^ ((row & 7) << 3);
      gld_lds16(xb + (size_t)(t0c + row) * CONV_D + DI + g * 128 + colb, &Bsh[rowb][0]);
      gld_lds16(xb + (size_t)(t0c + row) * CONV_D + DI + NG * NN + g * 128 + colb, &Csh[rowb][0]);
    }
    {
      int s = tid & 63, pq = tid >> 6;
      const u16* xr = xb + (size_t)(t0c + s) * CONV_D + g * 512 + r * 64;
      #pragma unroll
      for (int pb = 0; pb < 4; ++pb) {
        int p0 = pb * 16 + pq * 4;
        u16x4 v = *(const u16x4*)&xr[p0];
        #pragma unroll
        for (int j = 0; j < 4; ++j) {
          int p = p0 + j;
          Xt[p][s ^ ((p & 7) << 3)] = v[j];
        }
      }
    }
    {
      int s = tid & 63, nq = tid >> 6;
      float wend = __expf(Lsh[t0c + 63] - Lsh[t0c + s]) * dtsh[t0c + s];
      const u16* br = xb + (size_t)(t0c + s) * CONV_D + DI + g * 128;
      #pragma unroll
      for (int nb = 0; nb < 8; ++nb) {
        int n0 = nb * 16 + nq * 4;
        u16x4 v = *(const u16x4*)&br[n0];
        #pragma unroll
        for (int j = 0; j < 4; ++j) {
          int n = n0 + j;
          Btw[n][s ^ ((n & 7) << 3)] = f2bf(bf2f(v[j]) * wend);
        }
      }
    }
    __syncthreads();

    s16x8 aC[4];
    #pragma unroll
    for (int k = 0; k < 4; ++k)
      aC[k] = *(const s16x8*)&Csh[w * 16 + (lane & 15)][(k * 32 + (lane >> 4) * 8) ^ swz];
    f32x4 Gacc[4];
    #pragma unroll
    for (int st = 0; st < 4; ++st) Gacc[st] = (f32x4){0.f, 0.f, 0.f, 0.f};
    #pragma unroll
    for (int st = 0; st < 4; ++st)
      #pragma unroll
      for (int k = 0; k < 4; ++k) {
        s16x8 bB = *(const s16x8*)&Bsh[st * 16 + (lane & 15)][(k * 32 + (lane >> 4) * 8) ^ swz];
        Gacc[st] = __builtin_amdgcn_mfma_f32_16x16x32_bf16(aC[k], bB, Gacc[st], 0, 0, 0);
      }
    #pragma unroll
    for (int st = 0; st < 4; ++st) {
      int s = st * 16 + (lane & 15);
      float Ls = Lsh[t0c + s], dts = dtsh[t0c + s];
      #pragma unroll
      for (int j = 0; j < 4; ++j) {
        int t = w * 16 + (lane >> 4) * 4 + j;
        float wgt = (s <= t) ? __expf(Lsh[t0c + t] - Ls) * dts : 0.f;
        GWsh[t][s ^ ((t & 7) << 3)] = f2bf(Gacc[st][j] * wgt);
      }
    }
    __syncthreads();

    f32x4 Yacc[4], Y2acc[4];
    #pragma unroll
    for (int pt = 0; pt < 4; ++pt) { Yacc[pt] = (f32x4){0.f,0.f,0.f,0.f}; Y2acc[pt] = (f32x4){0.f,0.f,0.f,0.f}; }
    s16x8 aGW[2];
    #pragma unroll
    for (int k = 0; k < 2; ++k)
      aGW[k] = *(const s16x8*)&GWsh[w * 16 + (lane & 15)][(k * 32 + (lane >> 4) * 8) ^ swz];
    #pragma unroll
    for (int pt = 0; pt < 4; ++pt) {
      #pragma unroll
      for (int k = 0; k < 2; ++k) {
        s16x8 bX = *(const s16x8*)&Xt[pt * 16 + (lane & 15)][(k * 32 + (lane >> 4) * 8) ^ swz];
        Yacc[pt] = __builtin_amdgcn_mfma_f32_16x16x32_bf16(aGW[k], bX, Yacc[pt], 0, 0, 0);
      }
      #pragma unroll
      for (int k = 0; k < 4; ++k) {
        s16x8 bH = *(const s16x8*)&Hbf[pt * 16 + (lane & 15)][(k * 32 + (lane >> 4) * 8) ^ swz];
        Y2acc[pt] = __builtin_amdgcn_mfma_f32_16x16x32_bf16(aC[k], bH, Y2acc[pt], 0, 0, 0);
      }
    }
    float el[4];
    #pragma unroll
    for (int j = 0; j < 4; ++j) el[j] = __expf(Lsh[t0c + w * 16 + (lane >> 4) * 4 + j]);
    #pragma unroll
    for (int pt = 0; pt < 4; ++pt) {
      int p = pt * 16 + (lane & 15);
      #pragma unroll
      for (int j = 0; j < 4; ++j) {
        int t = w * 16 + (lane >> 4) * 4 + j;
        float xv = bf2f(Xt[p][t ^ ((p & 7) << 3)]);
        float yv = Yacc[pt][j] + el[j] * Y2acc[pt][j] + Dv * xv;
        y[((size_t)b * LSEQ + t0c + t) * DI + g * 512 + r * 64 + p] = yv;
      }
    }
    float e63 = __expf(Lsh[t0c + 63]);
    s16x8 aX[2];
    #pragma unroll
    for (int k = 0; k < 2; ++k)
      aX[k] = *(const s16x8*)&Xt[w * 16 + (lane & 15)][(k * 32 + (lane >> 4) * 8) ^ swz];
    #pragma unroll
    for (int nt = 0; nt < 8; ++nt) {
      #pragma unroll
      for (int j = 0; j < 4; ++j) hst[nt][j] *= e63;
      #pragma unroll
      for (int k = 0; k < 2; ++k) {
        s16x8 bW = *(const s16x8*)&Btw[nt * 16 + (lane & 15)][(k * 32 + (lane >> 4) * 8) ^ swz];
        hst[nt] = __builtin_amdgcn_mfma_f32_16x16x32_bf16(aX[k], bW, hst[nt], 0, 0, 0);
      }
    }
    __syncthreads();
    #pragma unroll
    for (int nt = 0; nt < 8; ++nt) {
      int n = nt * 16 + (lane & 15);
      #pragma unroll
      for (int j = 0; j < 4; ++j) {
        int p = w * 16 + (lane >> 4) * 4 + j;
        Hbf[p][n ^ ((p & 7) << 3)] = f2bf(hst[nt][j]);
      }
    }
  }
}

// ---------- y2 = rmsnorm(y * silu(z)) * gw -> bf16 ----------
__global__ __launch_bounds__(256) void gate_kernel(const float* __restrict__ y, const float* __restrict__ proj,
        const float* __restrict__ gw, u16* __restrict__ y2) {
  int row = blockIdx.x;
  const float* yr = y + (size_t)row * DI;
  const float* zr = proj + (size_t)row * PROJ_P;
  int tid = threadIdx.x;
  f32x4 v[4];
  float s = 0.f;
  #pragma unroll
  for (int i = 0; i < 4; i++) {
    int off = i * 1024 + tid * 4;
    f32x4 a = *(const f32x4*)&yr[off];
    f32x4 z = *(const f32x4*)&zr[off];
    f32x4 t;
    t.x = a.x * (z.x / (1.f + expf(-z.x)));
    t.y = a.y * (z.y / (1.f + expf(-z.y)));
    t.z = a.z * (z.z / (1.f + expf(-z.z)));
    t.w = a.w * (z.w / (1.f + expf(-z.w)));
    v[i] = t;
    s += t.x * t.x + t.y * t.y + t.z * t.z + t.w * t.w;
  }
  s = blockReduceSum256(s);
  float rs = rsqrtf(s * (1.f / DI) + 1e-5f);
  #pragma unroll
  for (int i = 0; i < 4; i++) {
    int off = i * 1024 + tid * 4;
    f32x4 wv = *(const f32x4*)&gw[off];
    u16x4 o;
    o.x = f2bf(v[i].x * rs * wv.x);
    o.y = f2bf(v[i].y * rs * wv.y);
    o.z = f2bf(v[i].z * rs * wv.z);
    o.w = f2bf(v[i].w * rs * wv.w);
    *(u16x4*)&y2[(size_t)row * DI + off] = o;
  }
}

extern "C" void kernel_launch(void* const* d_in, const int* in_sizes, int n_in,
                              void* d_out, int out_size, void* d_ws, size_t ws_size,
                              hipStream_t stream) {
  (void)in_sizes; (void)n_in; (void)out_size; (void)ws_size;
  const float* hs      = (const float*)d_in[0];
  const float* res     = (const float*)d_in[1];
  const float* norm_w  = (const float*)d_in[2];
  const float* w_in    = (const float*)d_in[3];
  const float* conv_w  = (const float*)d_in[4];
  const float* conv_b  = (const float*)d_in[5];
  const float* A_log   = (const float*)d_in[6];
  const float* D_param = (const float*)d_in[7];
  const float* dt_bias = (const float*)d_in[8];
  const float* gate_w  = (const float*)d_in[9];
  const float* w_out   = (const float*)d_in[10];

  float* out  = (float*)d_out;
  float* nres = out + (size_t)TOK * DM;

  char* ws = (char*)d_ws;
  size_t off = 0;
  u16*   WB1  = (u16*)(ws + off);   off += (size_t)PROJ_P * DM * 2;
  u16*   WB2  = (u16*)(ws + off);   off += (size_t)DM * DI * 2;
  u16*   XBF  = (u16*)(ws + off);   off += (size_t)TOK * DM * 2;
  float* PROJ = (float*)(ws + off); off += (size_t)TOK * PROJ_P * 4;
  u16*   XBC  = (u16*)(ws + off);   off += (size_t)TOK * CONV_D * 4;
  float* DTSP = (float*)(ws + off); off += (size_t)TOK * 64 * 4;
  float* DTA  = (float*)(ws + off); off += (size_t)TOK * 64 * 4;
  float* Y    = (float*)(ws + off); off += (size_t)TOK * DI * 4;
  u16*   Y2   = (u16*)(ws + off);   off += (size_t)TOK * DI * 2;

  // weight conversions
  cvt_bf16_pad<<<20992, 256, 0, stream>>>(w_in, WB1, (long)PROJ_D * DM, (long)PROJ_P * DM);
  cvt_bf16_pad<<<8192, 256, 0, stream>>>(w_out, WB2, (long)DM * DI, (long)DM * DI);
  // residual add + rmsnorm
  addnorm_kernel<<<TOK, 256, 0, stream>>>(hs, res, norm_w, nres, XBF);
  // in_proj GEMM: (2048 x 2048) x (10496 x 2048)^T -> 2048 x 10496, 8-phase 256^2
  gemm8p<<<(TOK / 256) * (PROJ_P / 256), 512, 0, stream>>>(XBF, WB1, PROJ, DM, PROJ_P, PROJ_P / 256);
  // conv + silu on xBC slice -> bf16
  conv_silu_kernel<<<(TOK * (CONV_D / 4)) / 256, 256, 0, stream>>>(PROJ, conv_w, conv_b, XBC);
  // dt softplus + log-decay (transposed layout)
  dt_kernel<<<(TOK * 64) / 256, 256, 0, stream>>>(PROJ, dt_bias, A_log, DTSP, DTA);
  // chunked SSD scan (+ D*xs): 128 blocks = (b,h)
  ssd_kernel<<<128, 256, 0, stream>>>(XBC, DTSP, DTA, D_param, Y);
  // gated rmsnorm -> bf16
  gate_kernel<<<TOK, 256, 0, stream>>>(Y, PROJ, gate_w, Y2);
  // out_proj GEMM: (2048 x 4096) x (2048 x 4096)^T -> 2048 x 2048, grid = 256 = 1/CU
  gemm_pipe<128, 128><<<(TOK / 128) * (DM / 128), 256, 0, stream>>>(Y2, WB2, out, DI, DM, DM / 128);
}